// Round 7
// baseline (193.382 us; speedup 1.0000x reference)
//
#include <hip/hip_runtime.h>
#include <math.h>

#define N_NODES 10000
#define N_EDGES 100000
#define HIDDEN  128
#define NHEAD   4
#define CHAN    128
#define IN_DIM  137      // 128 + 6 + 3
#define KPAD    160      // padded K for MFMA
#define NCOLS   1904     // 512*3 + 128 + 240
#define NPAD    1920     // padded to 15*128
#define LATD    6
#define DISD    3

#define PREP_BLOCKS 2500                       // 4 nodes/block
#define WTOT   (NCOLS * KPAD + 4 * 128 * 64)   // weights threads: 337408
#define WBLOCKS ((WTOT + 255) / 256)           // 1318

typedef __attribute__((ext_vector_type(8))) short short8v;
typedef __attribute__((ext_vector_type(4))) float float4v;

__device__ inline unsigned short f2bf(float f) {
    unsigned u = __float_as_uint(f);
    unsigned r = 0x7fffu + ((u >> 16) & 1u);
    return (unsigned short)((u + r) >> 16);
}
__device__ inline float bf2f(unsigned short u) {
    return __uint_as_float(((unsigned)u) << 16);
}

// ---------------- Kernel 1: prep (LN+concat+hist-zero) ∥ weights -------------
__global__ __launch_bounds__(256) void prep_weights_kernel(
    const float* __restrict__ nf, const float* __restrict__ frac,
    const float* __restrict__ lat, const int* __restrict__ n2g,
    const float* __restrict__ gamma, const float* __restrict__ beta,
    const float* __restrict__ Wq, const float* __restrict__ bq,
    const float* __restrict__ Wk, const float* __restrict__ bk,
    const float* __restrict__ Wv, const float* __restrict__ bv,
    const float* __restrict__ Wsk, const float* __restrict__ bsk,
    const float* __restrict__ We,
    unsigned short* __restrict__ xb, int* __restrict__ hist,
    unsigned short* __restrict__ wallT, float* __restrict__ bias_all,
    unsigned short* __restrict__ webt)
{
    if (blockIdx.x < PREP_BLOCKS) {
        // ---- prep: LayerNorm + concat -> bf16 x[N][160]; zero hist ----
        int wave = threadIdx.x >> 6;
        int lane = threadIdx.x & 63;
        int n = blockIdx.x * 4 + wave;
        if (n >= N_NODES) return;

        float v0 = nf[n * HIDDEN + lane];
        float v1 = nf[n * HIDDEN + 64 + lane];
        float s  = v0 + v1;
        float sq = v0 * v0 + v1 * v1;
        #pragma unroll
        for (int m = 1; m < 64; m <<= 1) {
            s  += __shfl_xor(s, m);
            sq += __shfl_xor(sq, m);
        }
        float mean = s * (1.0f / 128.0f);
        float var  = sq * (1.0f / 128.0f) - mean * mean;   // biased variance
        float inv  = rsqrtf(var + 1e-5f);

        xb[n * KPAD + lane]      = f2bf((v0 - mean) * inv * gamma[lane]      + beta[lane]);
        xb[n * KPAD + 64 + lane] = f2bf((v1 - mean) * inv * gamma[64 + lane] + beta[64 + lane]);
        if (lane < LATD) xb[n * KPAD + HIDDEN + lane]        = f2bf(lat[n2g[n] * LATD + lane]);
        if (lane < DISD) xb[n * KPAD + HIDDEN + LATD + lane] = f2bf(frac[n * DISD + lane]);
        if (lane >= 41)  xb[n * KPAD + 96 + lane] = 0;      // cols 137..159 zero-pad
        if (lane == 0)   hist[n] = 0;
    } else {
        // ---- weights: wallT bf16 (q,k,v,skip + fused Wqe) + biases + webt ----
        int idx = (blockIdx.x - PREP_BLOCKS) * 256 + threadIdx.x;
        if (idx >= WTOT) return;
        if (idx < NCOLS * KPAD) {
            int n = idx / KPAD, k = idx % KPAD;
            if (n < 1664) {
                float val = 0.0f;
                if (k < IN_DIM) {
                    if (n < 512)        val = Wq[(size_t)k * 512 + n];
                    else if (n < 1024)  val = Wk[(size_t)k * 512 + (n - 512)];
                    else if (n < 1536)  val = Wv[(size_t)k * 512 + (n - 1024)];
                    else                val = Wsk[(size_t)k * 128 + (n - 1536)];
                }
                wallT[idx] = f2bf(val);
                if (k == 0) {
                    float b;
                    if (n < 512)        b = bq[n];
                    else if (n < 1024)  b = bk[n - 512];
                    else if (n < 1536)  b = bv[n - 1024];
                    else                b = bsk[n - 1536];
                    bias_all[n] = b;
                }
            } else {
                int hj = n - 1664;                      // 0..239
                int h = hj / 60, j = hj % 60;
                float s = 0.0f;
                if (k < IN_DIM) {
                    #pragma unroll 4
                    for (int c = 0; c < 128; ++c)
                        s += Wq[(size_t)k * 512 + h * 128 + c] * We[(size_t)j * 512 + h * 128 + c];
                }
                wallT[idx] = f2bf(s);
                if (k == KPAD - 1) {
                    float b = 0.0f;
                    #pragma unroll 4
                    for (int c = 0; c < 128; ++c)
                        b += bq[h * 128 + c] * We[(size_t)j * 512 + h * 128 + c];
                    bias_all[n] = b;
                }
            }
        } else {
            int g = idx - NCOLS * KPAD;                 // webt[h][c][j], 4*128*64
            int h = g >> 13, c = (g >> 6) & 127, j = g & 63;
            float v = (j < 60) ? We[(size_t)j * 512 + h * 128 + c] : 0.0f;
            webt[g] = f2bf(v);
        }
    }
}

// ---------------- Kernel 0b: histogram of dst -------------------------------
__global__ __launch_bounds__(256) void hist_kernel(
    const int* __restrict__ eidx, int* __restrict__ hist)
{
    int e = blockIdx.x * 256 + threadIdx.x;
    if (e < N_EDGES) atomicAdd(&hist[eidx[N_EDGES + e]], 1);
}

// ---------------- Kernel 0c: exclusive scan (single block) ------------------
__global__ __launch_bounds__(1024) void scan_kernel(
    const int* __restrict__ hist, int* __restrict__ offsets, int* __restrict__ cursor)
{
    __shared__ int part[1024];
    const int t = threadIdx.x;
    const int base = t * 10;
    int loc[10];
    int s = 0;
    #pragma unroll
    for (int i = 0; i < 10; ++i) {
        int v = (base + i < N_NODES) ? hist[base + i] : 0;
        loc[i] = s; s += v;
    }
    part[t] = s;
    __syncthreads();
    for (int off = 1; off < 1024; off <<= 1) {
        int v = (t >= off) ? part[t - off] : 0;
        __syncthreads();
        part[t] += v;
        __syncthreads();
    }
    int pre = (t > 0) ? part[t - 1] : 0;
    #pragma unroll
    for (int i = 0; i < 10; ++i)
        if (base + i < N_NODES) {
            offsets[base + i] = pre + loc[i];
            cursor[base + i]  = pre + loc[i];
        }
    if (t == 1023) offsets[N_NODES] = part[1023];
}

// ---------------- Kernel 0d: scatter edges into dst-sorted order ------------
__global__ __launch_bounds__(256) void scatter_kernel(
    const int* __restrict__ eidx, const float* __restrict__ fdiff,
    int* __restrict__ cursor, int* __restrict__ sorted_src,
    float* __restrict__ sorted_fd)
{
    int e = blockIdx.x * 256 + threadIdx.x;
    if (e >= N_EDGES) return;
    int src = eidx[e];
    int dst = eidx[N_EDGES + e];
    int pos = atomicAdd(&cursor[dst], 1);
    sorted_src[pos] = src;
    sorted_fd[pos * 3 + 0] = fdiff[e * 3 + 0];
    sorted_fd[pos * 3 + 1] = fdiff[e * 3 + 1];
    sorted_fd[pos * 3 + 2] = fdiff[e * 3 + 2];
}

// ---------------- Kernel 3: MFMA GEMM xb[N,160] @ WallT^T --------------------
// A (64x160) staged in LDS; B fragments read DIRECTLY from global (wallT is
// [col][k] = exact fragment layout, L2-resident). q,k,v -> kvq bf16;
// skip,qe -> sq f32 [N][384] (skip 0..127, qe 128..367).
__global__ __launch_bounds__(256) void mfma_gemm_kernel(
    const unsigned short* __restrict__ xb, const unsigned short* __restrict__ wallT,
    const float* __restrict__ bias_all,
    float* __restrict__ sq, unsigned short* __restrict__ kvq)
{
    __shared__ __align__(16) unsigned short Alds[64 * 168];
    const int row0 = blockIdx.y * 64;
    const int col0 = blockIdx.x * 128;
    const int tid  = threadIdx.x;

    for (int i = tid; i < 64 * 20; i += 256) {       // A: 64 rows x 160 bf16
        int r = i / 20, c8 = (i % 20) * 8;
        uint4 v = make_uint4(0u, 0u, 0u, 0u);
        if (row0 + r < N_NODES)
            v = *reinterpret_cast<const uint4*>(&xb[(size_t)(row0 + r) * KPAD + c8]);
        *reinterpret_cast<uint4*>(&Alds[r * 168 + c8]) = v;
    }
    __syncthreads();

    const int l   = tid & 63;
    const int wid = tid >> 6;
    const int wr  = (wid >> 1) * 32;
    const int wc  = (wid & 1) * 64;
    const int lr  = l & 15;
    const int lk  = (l >> 4) * 8;

    float4v acc[2][4];
    #pragma unroll
    for (int tr = 0; tr < 2; ++tr)
        #pragma unroll
        for (int tc = 0; tc < 4; ++tc)
            acc[tr][tc] = (float4v){0.0f, 0.0f, 0.0f, 0.0f};

    #pragma unroll
    for (int ks = 0; ks < 5; ++ks) {
        short8v a[2], b[4];
        #pragma unroll
        for (int t = 0; t < 2; ++t)
            a[t] = *reinterpret_cast<const short8v*>(&Alds[(wr + t * 16 + lr) * 168 + ks * 32 + lk]);
        #pragma unroll
        for (int t = 0; t < 4; ++t)
            b[t] = *reinterpret_cast<const short8v*>(
                &wallT[(size_t)(col0 + wc + t * 16 + lr) * KPAD + ks * 32 + lk]);
        #pragma unroll
        for (int tr = 0; tr < 2; ++tr)
            #pragma unroll
            for (int tc = 0; tc < 4; ++tc)
                acc[tr][tc] = __builtin_amdgcn_mfma_f32_16x16x32_bf16(a[tr], b[tc], acc[tr][tc], 0, 0, 0);
    }

    #pragma unroll
    for (int tr = 0; tr < 2; ++tr) {
        #pragma unroll
        for (int tc = 0; tc < 4; ++tc) {
            const int col  = col0 + wc + tc * 16 + lr;
            const float bias = bias_all[col];
            #pragma unroll
            for (int j = 0; j < 4; ++j) {
                const int row = row0 + wr + tr * 16 + (l >> 4) * 4 + j;
                if (row < N_NODES) {
                    float val = acc[tr][tc][j] + bias;
                    if (col < 1536)                              // q,k,v -> bf16
                        kvq[(size_t)row * 1536 + col] = f2bf(val);
                    else if (col < 1664)                         // skip -> f32
                        sq[(size_t)row * 384 + (col - 1536)] = val;
                    else if (col < NCOLS)                        // qe -> f32
                        sq[(size_t)row * 384 + 128 + (col - 1664)] = val;
                }
            }
        }
    }
}

// ---------------- Kernel 4: per-node gather (no barrier, separate bufs) ------
// Block = 1 node, wave = head, half-wave per edge, unroll 2.
__global__ __launch_bounds__(256) void gather_kernel(
    const float* __restrict__ sq, const unsigned short* __restrict__ kvq,
    const int* __restrict__ offsets, const int* __restrict__ sorted_src,
    const float* __restrict__ sorted_fd,
    float* __restrict__ avbuf, unsigned short* __restrict__ aggbuf,
    float* __restrict__ sumwbuf)
{
    const int n    = blockIdx.x;
    const int h    = threadIdx.x >> 6;
    const int l    = threadIdx.x & 63;
    const int hl   = l & 31;
    const int half = l >> 5;
    const float TWO_PI = 6.283185307179586f;
    const float scale  = 0.08838834764831845f;   // 1/sqrt(128)

    const ushort4 qv = *reinterpret_cast<const ushort4*>(
        &kvq[(size_t)n * 1536 + h * 128 + 4 * hl]);
    const float q4x = bf2f(qv.x), q4y = bf2f(qv.y);
    const float q4z = bf2f(qv.z), q4w = bf2f(qv.w);
    const float qe_a = sq[(size_t)n * 384 + 128 + h * 60 + hl];  // j1 = hl (<60)
    const bool  v2ok = (hl < 28);                                // j2 = hl+32 < 60
    const float qe_b = v2ok ? sq[(size_t)n * 384 + 128 + h * 60 + hl + 32] : 0.0f;

    // emb slot 1: j1 = hl; slot 2: j2 = hl+32 (always cos)
    const int   jj1  = (hl < 30) ? hl : hl - 30;
    const int   sd1  = jj1 / 10;
    const float fc1  = TWO_PI * (float)(jj1 % 10);
    const bool  sin1 = (hl < 30);
    const int   jj2  = hl + 2;
    const int   sd2  = v2ok ? (jj2 / 10) : 0;
    const float fc2  = v2ok ? TWO_PI * (float)(jj2 % 10) : 0.0f;

    float ax = 0.f, ay = 0.f, az = 0.f, aw = 0.f;
    float agg1 = 0.f, agg2 = 0.f, sumw = 0.f;
    const int e0 = offsets[n], e1 = offsets[n + 1];

    for (int base = e0; base < e1; base += 4) {
        const int eA = base + half;
        const int eB = base + half + 2;
        const bool okA = (eA < e1), okB = (eB < e1);
        const int iA = okA ? eA : e0;
        const int iB = okB ? eB : e0;
        const int srcA = sorted_src[iA];
        const int srcB = sorted_src[iB];
        const float fdA1 = sorted_fd[iA * 3 + sd1];
        const float fdA2 = sorted_fd[iA * 3 + sd2];
        const float fdB1 = sorted_fd[iB * 3 + sd1];
        const float fdB2 = sorted_fd[iB * 3 + sd2];
        const unsigned short* pA = &kvq[(size_t)srcA * 1536 + 512 + h * 128 + 4 * hl];
        const unsigned short* pB = &kvq[(size_t)srcB * 1536 + 512 + h * 128 + 4 * hl];
        const ushort4 kA = *reinterpret_cast<const ushort4*>(pA);
        const ushort4 vA = *reinterpret_cast<const ushort4*>(pA + 512);
        const ushort4 kB = *reinterpret_cast<const ushort4*>(pB);
        const ushort4 vB = *reinterpret_cast<const ushort4*>(pB + 512);

        const float eA1 = sin1 ? __sinf(fdA1 * fc1) : __cosf(fdA1 * fc1);
        const float eA2 = __cosf(fdA2 * fc2);
        const float eB1 = sin1 ? __sinf(fdB1 * fc1) : __cosf(fdB1 * fc1);
        const float eB2 = __cosf(fdB2 * fc2);

        float pAs = q4x * bf2f(kA.x) + q4y * bf2f(kA.y)
                  + q4z * bf2f(kA.z) + q4w * bf2f(kA.w)
                  + eA1 * qe_a + eA2 * qe_b;
        float pBs = q4x * bf2f(kB.x) + q4y * bf2f(kB.y)
                  + q4z * bf2f(kB.z) + q4w * bf2f(kB.w)
                  + eB1 * qe_a + eB2 * qe_b;
        #pragma unroll
        for (int m = 1; m <= 16; m <<= 1) {
            pAs += __shfl_xor(pAs, m);
            pBs += __shfl_xor(pBs, m);
        }
        const float wA = okA ? __expf(pAs * scale) : 0.0f;
        const float wB = okB ? __expf(pBs * scale) : 0.0f;
        sumw += wA + wB;
        ax += wA * bf2f(vA.x) + wB * bf2f(vB.x);
        ay += wA * bf2f(vA.y) + wB * bf2f(vB.y);
        az += wA * bf2f(vA.z) + wB * bf2f(vB.z);
        aw += wA * bf2f(vA.w) + wB * bf2f(vB.w);
        agg1 += wA * eA1 + wB * eB1;
        if (v2ok) agg2 += wA * eA2 + wB * eB2;
    }

    // combine the two halves
    sumw += __shfl_xor(sumw, 32);
    ax += __shfl_xor(ax, 32);  ay += __shfl_xor(ay, 32);
    az += __shfl_xor(az, 32);  aw += __shfl_xor(aw, 32);
    agg1 += __shfl_xor(agg1, 32);
    agg2 += __shfl_xor(agg2, 32);

    if (half == 0) {
        float4 r;
        r.x = ax; r.y = ay; r.z = az; r.w = aw;
        *reinterpret_cast<float4*>(&avbuf[(size_t)n * 512 + h * 128 + 4 * hl]) = r;
        aggbuf[n * 256 + h * 64 + hl]      = f2bf(agg1);           // j = hl
        aggbuf[n * 256 + h * 64 + 32 + hl] = f2bf(agg2);           // j = hl+32
        if (hl == 0) sumwbuf[n * 4 + h] = sumw;
    }
}

// ---------------- Kernel 5: corr MFMA + finalize (fused) ---------------------
// Block = 32 nodes, 4 waves (wave h = head h). corr_h = aggemb_h @ Webt_h via
// MFMA (B direct from global). Then cross-head reduce in LDS (4 phases),
// z = 0.25*Σ_h (av_h+corr_h)/sumw_h + skip; out = nf + silu(z).
__global__ __launch_bounds__(256) void corrfin_kernel(
    const unsigned short* __restrict__ webt, const unsigned short* __restrict__ aggbuf,
    const float* __restrict__ avbuf, const float* __restrict__ sumwbuf,
    const float* __restrict__ sq, const float* __restrict__ nf,
    float* __restrict__ out)
{
    __shared__ __align__(16) unsigned short Alds[32 * 264];
    __shared__ float zbuf[32 * 128];
    const int node0 = blockIdx.x * 32;
    const int tid = threadIdx.x;

    for (int i = tid; i < 32 * 32; i += 256) {       // A: aggemb 32x256 bf16
        int r = i >> 5, c8 = (i & 31) * 8;
        uint4 v = make_uint4(0u, 0u, 0u, 0u);
        if (node0 + r < N_NODES)
            v = *reinterpret_cast<const uint4*>(&aggbuf[(size_t)(node0 + r) * 256 + c8]);
        *reinterpret_cast<uint4*>(&Alds[r * 264 + c8]) = v;
    }
    for (int i = tid; i < 32 * 128; i += 256) zbuf[i] = 0.0f;
    __syncthreads();

    const int l  = tid & 63;
    const int h  = tid >> 6;
    const int lr = l & 15;
    const int lk = (l >> 4) * 8;

    float4v acc[2][8];
    #pragma unroll
    for (int m = 0; m < 2; ++m)
        #pragma unroll
        for (int nn = 0; nn < 8; ++nn)
            acc[m][nn] = (float4v){0.0f, 0.0f, 0.0f, 0.0f};

    #pragma unroll
    for (int ks = 0; ks < 2; ++ks) {
        short8v a[2], b[8];
        #pragma unroll
        for (int m = 0; m < 2; ++m)
            a[m] = *reinterpret_cast<const short8v*>(
                &Alds[(m * 16 + lr) * 264 + h * 64 + ks * 32 + lk]);
        #pragma unroll
        for (int nn = 0; nn < 8; ++nn)
            b[nn] = *reinterpret_cast<const short8v*>(
                &webt[(size_t)(h * 128 + nn * 16 + lr) * 64 + ks * 32 + lk]);
        #pragma unroll
        for (int m = 0; m < 2; ++m)
            #pragma unroll
            for (int nn = 0; nn < 8; ++nn)
                acc[m][nn] = __builtin_amdgcn_mfma_f32_16x16x32_bf16(a[m], b[nn], acc[m][nn], 0, 0, 0);
    }

    // cross-head accumulation: (av + corr)/sumw added per head in 4 phases
    for (int ph = 0; ph < 4; ++ph) {
        if (ph == h) {
            #pragma unroll
            for (int m = 0; m < 2; ++m) {
                #pragma unroll
                for (int nn = 0; nn < 8; ++nn) {
                    const int col = nn * 16 + lr;
                    #pragma unroll
                    for (int j = 0; j < 4; ++j) {
                        const int r = m * 16 + (l >> 4) * 4 + j;
                        const int gn = node0 + r;
                        if (gn < N_NODES) {
                            const float sw = sumwbuf[gn * 4 + h] + 1e-16f;
                            const float val = (avbuf[(size_t)gn * 512 + h * 128 + col]
                                               + acc[m][nn][j]) / sw;
                            zbuf[r * 128 + col] += val;
                        }
                    }
                }
            }
        }
        __syncthreads();
    }

    // finalize: z = 0.25*Σ + skip; out = nf + silu(z)
    for (int i = tid; i < 32 * 128; i += 256) {
        const int r = i >> 7, c = i & 127;
        const int gn = node0 + r;
        if (gn < N_NODES) {
            float z = 0.25f * zbuf[i] + sq[(size_t)gn * 384 + c];
            float si = z / (1.0f + __expf(-z));
            out[gn * CHAN + c] = nf[gn * CHAN + c] + si;
        }
    }
}

// ---------------- launcher ---------------------------------------------------
extern "C" void kernel_launch(void* const* d_in, const int* in_sizes, int n_in,
                              void* d_out, int out_size, void* d_ws, size_t ws_size,
                              hipStream_t stream)
{
    const float* nf    = (const float*)d_in[0];
    const float* frac  = (const float*)d_in[1];
    const float* lat   = (const float*)d_in[2];
    const int*   eidx  = (const int*)  d_in[3];
    const int*   n2g   = (const int*)  d_in[4];
    const float* fdiff = (const float*)d_in[5];
    const float* gamma = (const float*)d_in[6];
    const float* beta  = (const float*)d_in[7];
    const float* Wq    = (const float*)d_in[8];
    const float* bq    = (const float*)d_in[9];
    const float* Wk    = (const float*)d_in[10];
    const float* bk    = (const float*)d_in[11];
    const float* Wv    = (const float*)d_in[12];
    const float* bv    = (const float*)d_in[13];
    const float* We    = (const float*)d_in[14];
    const float* Wsk   = (const float*)d_in[15];
    const float* bsk   = (const float*)d_in[16];
    float* out = (float*)d_out;

    // workspace layout
    float* sq        = (float*)d_ws;                               // N*384 (skip,qe)
    float* avbuf     = sq + (size_t)N_NODES * 384;                 // N*512
    float* sumwbuf   = avbuf + (size_t)N_NODES * 512;              // N*4
    float* bias_all  = sumwbuf + (size_t)N_NODES * 4;              // 1920
    float* sorted_fd = bias_all + NPAD;                            // E*3
    unsigned short* xb     = (unsigned short*)(sorted_fd + (size_t)N_EDGES * 3); // N*160
    unsigned short* wallT  = xb + (size_t)N_NODES * KPAD;          // 1920*160
    unsigned short* webt   = wallT + (size_t)NPAD * KPAD;          // 4*128*64
    unsigned short* aggbuf = webt + 4 * 128 * 64;                  // N*256
    unsigned short* kvq    = aggbuf + (size_t)N_NODES * 256;       // N*1536
    int* hist       = (int*)(kvq + (size_t)N_NODES * 1536);        // N
    int* offsets    = hist + N_NODES;                              // N+1
    int* cursor     = offsets + N_NODES + 1;                       // N
    int* sorted_src = cursor + N_NODES;                            // E

    prep_weights_kernel<<<PREP_BLOCKS + WBLOCKS, 256, 0, stream>>>(
        nf, frac, lat, n2g, gamma, beta,
        Wq, bq, Wk, bk, Wv, bv, Wsk, bsk, We,
        xb, hist, wallT, bias_all, webt);

    hist_kernel<<<(N_EDGES + 255) / 256, 256, 0, stream>>>(eidx, hist);
    scan_kernel<<<1, 1024, 0, stream>>>(hist, offsets, cursor);
    scatter_kernel<<<(N_EDGES + 255) / 256, 256, 0, stream>>>(
        eidx, fdiff, cursor, sorted_src, sorted_fd);

    dim3 ggrid(NPAD / 128, (N_NODES + 63) / 64);
    mfma_gemm_kernel<<<ggrid, 256, 0, stream>>>(xb, wallT, bias_all, sq, kvq);

    gather_kernel<<<N_NODES, 256, 0, stream>>>(
        sq, kvq, offsets, sorted_src, sorted_fd, avbuf, aggbuf, sumwbuf);

    corrfin_kernel<<<(N_NODES + 31) / 32, 256, 0, stream>>>(
        webt, aggbuf, avbuf, sumwbuf, sq, nf, out);
}

// Round 8
// 152.706 us; speedup vs baseline: 1.2664x; 1.2664x over previous
//
#include <hip/hip_runtime.h>
#include <math.h>

#define N_NODES 10000
#define N_EDGES 100000
#define HIDDEN  128
#define NHEAD   4
#define CHAN    128
#define IN_DIM  137      // 128 + 6 + 3
#define KPAD    160      // padded K for MFMA
#define NCOLS   1904     // 512*3 + 128 + 240
#define NPAD    1920     // padded to 15*128
#define LATD    6
#define DISD    3

#define PREP_BLOCKS 2500                       // 4 nodes/block
#define WTOT   (NCOLS * KPAD + 4 * 128 * 64)   // weights threads: 337408
#define WBLOCKS ((WTOT + 255) / 256)           // 1318

typedef __attribute__((ext_vector_type(8))) short short8v;
typedef __attribute__((ext_vector_type(4))) float float4v;

__device__ inline unsigned short f2bf(float f) {
    unsigned u = __float_as_uint(f);
    unsigned r = 0x7fffu + ((u >> 16) & 1u);
    return (unsigned short)((u + r) >> 16);
}
__device__ inline float bf2f(unsigned short u) {
    return __uint_as_float(((unsigned)u) << 16);
}

// ---------------- Kernel 1: prep (LN+concat+hist-zero) ∥ weights -------------
__global__ __launch_bounds__(256) void prep_weights_kernel(
    const float* __restrict__ nf, const float* __restrict__ frac,
    const float* __restrict__ lat, const int* __restrict__ n2g,
    const float* __restrict__ gamma, const float* __restrict__ beta,
    const float* __restrict__ Wq, const float* __restrict__ bq,
    const float* __restrict__ Wk, const float* __restrict__ bk,
    const float* __restrict__ Wv, const float* __restrict__ bv,
    const float* __restrict__ Wsk, const float* __restrict__ bsk,
    const float* __restrict__ We,
    unsigned short* __restrict__ xb, int* __restrict__ hist,
    unsigned short* __restrict__ wallT, float* __restrict__ bias_all,
    unsigned short* __restrict__ webt)
{
    if (blockIdx.x < PREP_BLOCKS) {
        // ---- prep: LayerNorm + concat -> bf16 x[N][160]; zero hist ----
        int wave = threadIdx.x >> 6;
        int lane = threadIdx.x & 63;
        int n = blockIdx.x * 4 + wave;
        if (n >= N_NODES) return;

        float v0 = nf[n * HIDDEN + lane];
        float v1 = nf[n * HIDDEN + 64 + lane];
        float s  = v0 + v1;
        float sq = v0 * v0 + v1 * v1;
        #pragma unroll
        for (int m = 1; m < 64; m <<= 1) {
            s  += __shfl_xor(s, m);
            sq += __shfl_xor(sq, m);
        }
        float mean = s * (1.0f / 128.0f);
        float var  = sq * (1.0f / 128.0f) - mean * mean;   // biased variance
        float inv  = rsqrtf(var + 1e-5f);

        xb[n * KPAD + lane]      = f2bf((v0 - mean) * inv * gamma[lane]      + beta[lane]);
        xb[n * KPAD + 64 + lane] = f2bf((v1 - mean) * inv * gamma[64 + lane] + beta[64 + lane]);
        if (lane < LATD) xb[n * KPAD + HIDDEN + lane]        = f2bf(lat[n2g[n] * LATD + lane]);
        if (lane < DISD) xb[n * KPAD + HIDDEN + LATD + lane] = f2bf(frac[n * DISD + lane]);
        if (lane >= 41)  xb[n * KPAD + 96 + lane] = 0;      // cols 137..159 zero-pad
        if (lane == 0)   hist[n] = 0;
    } else {
        // ---- weights: wallT bf16 (q,k,v,skip + fused Wqe) + biases + webt ----
        int idx = (blockIdx.x - PREP_BLOCKS) * 256 + threadIdx.x;
        if (idx >= WTOT) return;
        if (idx < NCOLS * KPAD) {
            int n = idx / KPAD, k = idx % KPAD;
            if (n < 1664) {
                float val = 0.0f;
                if (k < IN_DIM) {
                    if (n < 512)        val = Wq[(size_t)k * 512 + n];
                    else if (n < 1024)  val = Wk[(size_t)k * 512 + (n - 512)];
                    else if (n < 1536)  val = Wv[(size_t)k * 512 + (n - 1024)];
                    else                val = Wsk[(size_t)k * 128 + (n - 1536)];
                }
                wallT[idx] = f2bf(val);
                if (k == 0) {
                    float b;
                    if (n < 512)        b = bq[n];
                    else if (n < 1024)  b = bk[n - 512];
                    else if (n < 1536)  b = bv[n - 1024];
                    else                b = bsk[n - 1536];
                    bias_all[n] = b;
                }
            } else {
                int hj = n - 1664;                      // 0..239
                int h = hj / 60, j = hj % 60;
                float s = 0.0f;
                if (k < IN_DIM) {
                    #pragma unroll 4
                    for (int c = 0; c < 128; ++c)
                        s += Wq[(size_t)k * 512 + h * 128 + c] * We[(size_t)j * 512 + h * 128 + c];
                }
                wallT[idx] = f2bf(s);
                if (k == KPAD - 1) {
                    float b = 0.0f;
                    #pragma unroll 4
                    for (int c = 0; c < 128; ++c)
                        b += bq[h * 128 + c] * We[(size_t)j * 512 + h * 128 + c];
                    bias_all[n] = b;
                }
            }
        } else {
            int g = idx - NCOLS * KPAD;                 // webt[h][c][j], 4*128*64
            int h = g >> 13, c = (g >> 6) & 127, j = g & 63;
            float v = (j < 60) ? We[(size_t)j * 512 + h * 128 + c] : 0.0f;
            webt[g] = f2bf(v);
        }
    }
}

// ---------------- Kernel 0b: histogram of dst -------------------------------
__global__ __launch_bounds__(256) void hist_kernel(
    const int* __restrict__ eidx, int* __restrict__ hist)
{
    int e = blockIdx.x * 256 + threadIdx.x;
    if (e < N_EDGES) atomicAdd(&hist[eidx[N_EDGES + e]], 1);
}

// ---------------- Kernel 0c: exclusive scan (single block) ------------------
__global__ __launch_bounds__(1024) void scan_kernel(
    const int* __restrict__ hist, int* __restrict__ offsets, int* __restrict__ cursor)
{
    __shared__ int part[1024];
    const int t = threadIdx.x;
    const int base = t * 10;
    int loc[10];
    int s = 0;
    #pragma unroll
    for (int i = 0; i < 10; ++i) {
        int v = (base + i < N_NODES) ? hist[base + i] : 0;
        loc[i] = s; s += v;
    }
    part[t] = s;
    __syncthreads();
    for (int off = 1; off < 1024; off <<= 1) {
        int v = (t >= off) ? part[t - off] : 0;
        __syncthreads();
        part[t] += v;
        __syncthreads();
    }
    int pre = (t > 0) ? part[t - 1] : 0;
    #pragma unroll
    for (int i = 0; i < 10; ++i)
        if (base + i < N_NODES) {
            offsets[base + i] = pre + loc[i];
            cursor[base + i]  = pre + loc[i];
        }
    if (t == 1023) offsets[N_NODES] = part[1023];
}

// ---------------- Kernel 0d: scatter edges into dst-sorted order ------------
__global__ __launch_bounds__(256) void scatter_kernel(
    const int* __restrict__ eidx, const float* __restrict__ fdiff,
    int* __restrict__ cursor, int* __restrict__ sorted_src,
    float* __restrict__ sorted_fd)
{
    int e = blockIdx.x * 256 + threadIdx.x;
    if (e >= N_EDGES) return;
    int src = eidx[e];
    int dst = eidx[N_EDGES + e];
    int pos = atomicAdd(&cursor[dst], 1);
    sorted_src[pos] = src;
    sorted_fd[pos * 3 + 0] = fdiff[e * 3 + 0];
    sorted_fd[pos * 3 + 1] = fdiff[e * 3 + 1];
    sorted_fd[pos * 3 + 2] = fdiff[e * 3 + 2];
}

// ---------------- Kernel 3: MFMA GEMM xb[N,160] @ WallT^T --------------------
// A (64x160) staged in LDS; B fragments read DIRECTLY from global (wallT is
// [col][k] = exact fragment layout, L2-resident). q,k,v -> kvq bf16;
// skip,qe -> sq f32 [N][384] (skip 0..127, qe 128..367).
__global__ __launch_bounds__(256) void mfma_gemm_kernel(
    const unsigned short* __restrict__ xb, const unsigned short* __restrict__ wallT,
    const float* __restrict__ bias_all,
    float* __restrict__ sq, unsigned short* __restrict__ kvq)
{
    __shared__ __align__(16) unsigned short Alds[64 * 168];
    const int row0 = blockIdx.y * 64;
    const int col0 = blockIdx.x * 128;
    const int tid  = threadIdx.x;

    for (int i = tid; i < 64 * 20; i += 256) {       // A: 64 rows x 160 bf16
        int r = i / 20, c8 = (i % 20) * 8;
        uint4 v = make_uint4(0u, 0u, 0u, 0u);
        if (row0 + r < N_NODES)
            v = *reinterpret_cast<const uint4*>(&xb[(size_t)(row0 + r) * KPAD + c8]);
        *reinterpret_cast<uint4*>(&Alds[r * 168 + c8]) = v;
    }
    __syncthreads();

    const int l   = tid & 63;
    const int wid = tid >> 6;
    const int wr  = (wid >> 1) * 32;
    const int wc  = (wid & 1) * 64;
    const int lr  = l & 15;
    const int lk  = (l >> 4) * 8;

    float4v acc[2][4];
    #pragma unroll
    for (int tr = 0; tr < 2; ++tr)
        #pragma unroll
        for (int tc = 0; tc < 4; ++tc)
            acc[tr][tc] = (float4v){0.0f, 0.0f, 0.0f, 0.0f};

    #pragma unroll
    for (int ks = 0; ks < 5; ++ks) {
        short8v a[2], b[4];
        #pragma unroll
        for (int t = 0; t < 2; ++t)
            a[t] = *reinterpret_cast<const short8v*>(&Alds[(wr + t * 16 + lr) * 168 + ks * 32 + lk]);
        #pragma unroll
        for (int t = 0; t < 4; ++t)
            b[t] = *reinterpret_cast<const short8v*>(
                &wallT[(size_t)(col0 + wc + t * 16 + lr) * KPAD + ks * 32 + lk]);
        #pragma unroll
        for (int tr = 0; tr < 2; ++tr)
            #pragma unroll
            for (int tc = 0; tc < 4; ++tc)
                acc[tr][tc] = __builtin_amdgcn_mfma_f32_16x16x32_bf16(a[tr], b[tc], acc[tr][tc], 0, 0, 0);
    }

    #pragma unroll
    for (int tr = 0; tr < 2; ++tr) {
        #pragma unroll
        for (int tc = 0; tc < 4; ++tc) {
            const int col  = col0 + wc + tc * 16 + lr;
            const float bias = bias_all[col];
            #pragma unroll
            for (int j = 0; j < 4; ++j) {
                const int row = row0 + wr + tr * 16 + (l >> 4) * 4 + j;
                if (row < N_NODES) {
                    float val = acc[tr][tc][j] + bias;
                    if (col < 1536)                              // q,k,v -> bf16
                        kvq[(size_t)row * 1536 + col] = f2bf(val);
                    else if (col < 1664)                         // skip -> f32
                        sq[(size_t)row * 384 + (col - 1536)] = val;
                    else if (col < NCOLS)                        // qe -> f32
                        sq[(size_t)row * 384 + 128 + (col - 1664)] = val;
                }
            }
        }
    }
}

// ---------------- Kernel 4: per-node gather (no barrier, separate bufs) ------
// Block = 1 node, wave = head, half-wave per edge, unroll 2.
__global__ __launch_bounds__(256) void gather_kernel(
    const float* __restrict__ sq, const unsigned short* __restrict__ kvq,
    const int* __restrict__ offsets, const int* __restrict__ sorted_src,
    const float* __restrict__ sorted_fd,
    float* __restrict__ avbuf, unsigned short* __restrict__ aggbuf,
    float* __restrict__ sumwbuf)
{
    const int n    = blockIdx.x;
    const int h    = threadIdx.x >> 6;
    const int l    = threadIdx.x & 63;
    const int hl   = l & 31;
    const int half = l >> 5;
    const float TWO_PI = 6.283185307179586f;
    const float scale  = 0.08838834764831845f;   // 1/sqrt(128)

    const ushort4 qv = *reinterpret_cast<const ushort4*>(
        &kvq[(size_t)n * 1536 + h * 128 + 4 * hl]);
    const float q4x = bf2f(qv.x), q4y = bf2f(qv.y);
    const float q4z = bf2f(qv.z), q4w = bf2f(qv.w);
    const float qe_a = sq[(size_t)n * 384 + 128 + h * 60 + hl];  // j1 = hl (<60)
    const bool  v2ok = (hl < 28);                                // j2 = hl+32 < 60
    const float qe_b = v2ok ? sq[(size_t)n * 384 + 128 + h * 60 + hl + 32] : 0.0f;

    // emb slot 1: j1 = hl; slot 2: j2 = hl+32 (always cos)
    const int   jj1  = (hl < 30) ? hl : hl - 30;
    const int   sd1  = jj1 / 10;
    const float fc1  = TWO_PI * (float)(jj1 % 10);
    const bool  sin1 = (hl < 30);
    const int   jj2  = hl + 2;
    const int   sd2  = v2ok ? (jj2 / 10) : 0;
    const float fc2  = v2ok ? TWO_PI * (float)(jj2 % 10) : 0.0f;

    float ax = 0.f, ay = 0.f, az = 0.f, aw = 0.f;
    float agg1 = 0.f, agg2 = 0.f, sumw = 0.f;
    const int e0 = offsets[n], e1 = offsets[n + 1];

    for (int base = e0; base < e1; base += 4) {
        const int eA = base + half;
        const int eB = base + half + 2;
        const bool okA = (eA < e1), okB = (eB < e1);
        const int iA = okA ? eA : e0;
        const int iB = okB ? eB : e0;
        const int srcA = sorted_src[iA];
        const int srcB = sorted_src[iB];
        const float fdA1 = sorted_fd[iA * 3 + sd1];
        const float fdA2 = sorted_fd[iA * 3 + sd2];
        const float fdB1 = sorted_fd[iB * 3 + sd1];
        const float fdB2 = sorted_fd[iB * 3 + sd2];
        const unsigned short* pA = &kvq[(size_t)srcA * 1536 + 512 + h * 128 + 4 * hl];
        const unsigned short* pB = &kvq[(size_t)srcB * 1536 + 512 + h * 128 + 4 * hl];
        const ushort4 kA = *reinterpret_cast<const ushort4*>(pA);
        const ushort4 vA = *reinterpret_cast<const ushort4*>(pA + 512);
        const ushort4 kB = *reinterpret_cast<const ushort4*>(pB);
        const ushort4 vB = *reinterpret_cast<const ushort4*>(pB + 512);

        const float eA1 = sin1 ? __sinf(fdA1 * fc1) : __cosf(fdA1 * fc1);
        const float eA2 = __cosf(fdA2 * fc2);
        const float eB1 = sin1 ? __sinf(fdB1 * fc1) : __cosf(fdB1 * fc1);
        const float eB2 = __cosf(fdB2 * fc2);

        float pAs = q4x * bf2f(kA.x) + q4y * bf2f(kA.y)
                  + q4z * bf2f(kA.z) + q4w * bf2f(kA.w)
                  + eA1 * qe_a + eA2 * qe_b;
        float pBs = q4x * bf2f(kB.x) + q4y * bf2f(kB.y)
                  + q4z * bf2f(kB.z) + q4w * bf2f(kB.w)
                  + eB1 * qe_a + eB2 * qe_b;
        #pragma unroll
        for (int m = 1; m <= 16; m <<= 1) {
            pAs += __shfl_xor(pAs, m);
            pBs += __shfl_xor(pBs, m);
        }
        const float wA = okA ? __expf(pAs * scale) : 0.0f;
        const float wB = okB ? __expf(pBs * scale) : 0.0f;
        sumw += wA + wB;
        ax += wA * bf2f(vA.x) + wB * bf2f(vB.x);
        ay += wA * bf2f(vA.y) + wB * bf2f(vB.y);
        az += wA * bf2f(vA.z) + wB * bf2f(vB.z);
        aw += wA * bf2f(vA.w) + wB * bf2f(vB.w);
        agg1 += wA * eA1 + wB * eB1;
        if (v2ok) agg2 += wA * eA2 + wB * eB2;
    }

    // combine the two halves
    sumw += __shfl_xor(sumw, 32);
    ax += __shfl_xor(ax, 32);  ay += __shfl_xor(ay, 32);
    az += __shfl_xor(az, 32);  aw += __shfl_xor(aw, 32);
    agg1 += __shfl_xor(agg1, 32);
    agg2 += __shfl_xor(agg2, 32);

    if (half == 0) {
        float4 r;
        r.x = ax; r.y = ay; r.z = az; r.w = aw;
        *reinterpret_cast<float4*>(&avbuf[(size_t)n * 512 + h * 128 + 4 * hl]) = r;
        aggbuf[n * 256 + h * 64 + hl]      = f2bf(agg1);           // j = hl
        aggbuf[n * 256 + h * 64 + 32 + hl] = f2bf(agg2);           // j = hl+32
        if (hl == 0) sumwbuf[n * 4 + h] = sumw;
    }
}

// ---------------- Kernel 5: corr MFMA — avbuf += aggemb @ Webt ---------------
// Block = 32 nodes, 4 waves (wave h = head h). A: aggemb [32][256] bf16;
// B direct from global webt[h][128][64] (L2-resident, 128 KB).
__global__ __launch_bounds__(256) void corr_kernel(
    const unsigned short* __restrict__ webt, const unsigned short* __restrict__ aggbuf,
    float* __restrict__ avbuf)
{
    __shared__ __align__(16) unsigned short Alds[32 * 264];
    const int node0 = blockIdx.x * 32;
    const int tid = threadIdx.x;

    for (int i = tid; i < 32 * 32; i += 256) {       // A: 1024 uint4
        int r = i >> 5, c8 = (i & 31) * 8;
        uint4 v = make_uint4(0u, 0u, 0u, 0u);
        if (node0 + r < N_NODES)
            v = *reinterpret_cast<const uint4*>(&aggbuf[(size_t)(node0 + r) * 256 + c8]);
        *reinterpret_cast<uint4*>(&Alds[r * 264 + c8]) = v;
    }
    __syncthreads();

    const int l  = tid & 63;
    const int h  = tid >> 6;
    const int lr = l & 15;
    const int lk = (l >> 4) * 8;

    float4v acc[2][8];
    #pragma unroll
    for (int m = 0; m < 2; ++m)
        #pragma unroll
        for (int nn = 0; nn < 8; ++nn)
            acc[m][nn] = (float4v){0.0f, 0.0f, 0.0f, 0.0f};

    #pragma unroll
    for (int ks = 0; ks < 2; ++ks) {
        short8v a[2], b[8];
        #pragma unroll
        for (int m = 0; m < 2; ++m)
            a[m] = *reinterpret_cast<const short8v*>(
                &Alds[(m * 16 + lr) * 264 + h * 64 + ks * 32 + lk]);
        #pragma unroll
        for (int nn = 0; nn < 8; ++nn)
            b[nn] = *reinterpret_cast<const short8v*>(
                &webt[(size_t)(h * 128 + nn * 16 + lr) * 64 + ks * 32 + lk]);
        #pragma unroll
        for (int m = 0; m < 2; ++m)
            #pragma unroll
            for (int nn = 0; nn < 8; ++nn)
                acc[m][nn] = __builtin_amdgcn_mfma_f32_16x16x32_bf16(a[m], b[nn], acc[m][nn], 0, 0, 0);
    }

    #pragma unroll
    for (int m = 0; m < 2; ++m) {
        #pragma unroll
        for (int nn = 0; nn < 8; ++nn) {
            const int col = h * 128 + nn * 16 + lr;
            #pragma unroll
            for (int j = 0; j < 4; ++j) {
                const int rowi = node0 + m * 16 + (l >> 4) * 4 + j;
                if (rowi < N_NODES) {
                    float* p = &avbuf[(size_t)rowi * 512 + col];
                    *p += acc[m][nn][j];
                }
            }
        }
    }
}

// ---------------- Kernel 6: finalize ----------------------------------------
__global__ __launch_bounds__(256) void finalize_kernel(
    const float* __restrict__ avbuf, const float* __restrict__ sumwbuf,
    const float* __restrict__ sq, const float* __restrict__ nf,
    float* __restrict__ out)
{
    int idx = blockIdx.x * 256 + threadIdx.x;
    if (idx >= N_NODES * CHAN) return;
    int n = idx >> 7, c = idx & 127;
    float z = 0.0f;
    #pragma unroll
    for (int h = 0; h < NHEAD; ++h)
        z += avbuf[(size_t)n * 512 + h * 128 + c] / (sumwbuf[n * 4 + h] + 1e-16f);
    z = 0.25f * z + sq[(size_t)n * 384 + c];        // head mean + skip
    float si = z / (1.0f + __expf(-z));             // silu
    out[idx] = nf[idx] + si;
}

// ---------------- launcher ---------------------------------------------------
extern "C" void kernel_launch(void* const* d_in, const int* in_sizes, int n_in,
                              void* d_out, int out_size, void* d_ws, size_t ws_size,
                              hipStream_t stream)
{
    const float* nf    = (const float*)d_in[0];
    const float* frac  = (const float*)d_in[1];
    const float* lat   = (const float*)d_in[2];
    const int*   eidx  = (const int*)  d_in[3];
    const int*   n2g   = (const int*)  d_in[4];
    const float* fdiff = (const float*)d_in[5];
    const float* gamma = (const float*)d_in[6];
    const float* beta  = (const float*)d_in[7];
    const float* Wq    = (const float*)d_in[8];
    const float* bq    = (const float*)d_in[9];
    const float* Wk    = (const float*)d_in[10];
    const float* bk    = (const float*)d_in[11];
    const float* Wv    = (const float*)d_in[12];
    const float* bv    = (const float*)d_in[13];
    const float* We    = (const float*)d_in[14];
    const float* Wsk   = (const float*)d_in[15];
    const float* bsk   = (const float*)d_in[16];
    float* out = (float*)d_out;

    // workspace layout
    float* sq        = (float*)d_ws;                               // N*384 (skip,qe)
    float* avbuf     = sq + (size_t)N_NODES * 384;                 // N*512
    float* sumwbuf   = avbuf + (size_t)N_NODES * 512;              // N*4
    float* bias_all  = sumwbuf + (size_t)N_NODES * 4;              // 1920
    float* sorted_fd = bias_all + NPAD;                            // E*3
    unsigned short* xb     = (unsigned short*)(sorted_fd + (size_t)N_EDGES * 3); // N*160
    unsigned short* wallT  = xb + (size_t)N_NODES * KPAD;          // 1920*160
    unsigned short* webt   = wallT + (size_t)NPAD * KPAD;          // 4*128*64
    unsigned short* aggbuf = webt + 4 * 128 * 64;                  // N*256
    unsigned short* kvq    = aggbuf + (size_t)N_NODES * 256;       // N*1536
    int* hist       = (int*)(kvq + (size_t)N_NODES * 1536);        // N
    int* offsets    = hist + N_NODES;                              // N+1
    int* cursor     = offsets + N_NODES + 1;                       // N
    int* sorted_src = cursor + N_NODES;                            // E

    prep_weights_kernel<<<PREP_BLOCKS + WBLOCKS, 256, 0, stream>>>(
        nf, frac, lat, n2g, gamma, beta,
        Wq, bq, Wk, bk, Wv, bv, Wsk, bsk, We,
        xb, hist, wallT, bias_all, webt);

    hist_kernel<<<(N_EDGES + 255) / 256, 256, 0, stream>>>(eidx, hist);
    scan_kernel<<<1, 1024, 0, stream>>>(hist, offsets, cursor);
    scatter_kernel<<<(N_EDGES + 255) / 256, 256, 0, stream>>>(
        eidx, fdiff, cursor, sorted_src, sorted_fd);

    dim3 ggrid(NPAD / 128, (N_NODES + 63) / 64);
    mfma_gemm_kernel<<<ggrid, 256, 0, stream>>>(xb, wallT, bias_all, sq, kvq);

    gather_kernel<<<N_NODES, 256, 0, stream>>>(
        sq, kvq, offsets, sorted_src, sorted_fd, avbuf, aggbuf, sumwbuf);

    corr_kernel<<<(N_NODES + 31) / 32, 256, 0, stream>>>(webt, aggbuf, avbuf);

    finalize_kernel<<<(N_NODES * CHAN + 255) / 256, 256, 0, stream>>>(
        avbuf, sumwbuf, sq, nf, out);
}

// Round 9
// 148.286 us; speedup vs baseline: 1.3041x; 1.0298x over previous
//
#include <hip/hip_runtime.h>
#include <math.h>

#define N_NODES 10000
#define N_EDGES 100000
#define HIDDEN  128
#define NHEAD   4
#define CHAN    128
#define IN_DIM  137      // 128 + 6 + 3
#define KPAD    160      // padded K for MFMA
#define NCOLS   1904     // 512*3 + 128 + 240
#define NPAD    1920     // padded to 15*128
#define LATD    6
#define DISD    3

#define PREP_BLOCKS 2500                       // 4 nodes/block
#define WTOT   (NCOLS * KPAD + 4 * 128 * 64)   // weights threads: 337408
#define WBLOCKS ((WTOT + 255) / 256)           // 1318

#define SCAT_BLOCKS ((N_EDGES + 255) / 256)    // 391
#define GEMM_BX 15
#define GEMM_BY ((N_NODES + 63) / 64)          // 157

typedef __attribute__((ext_vector_type(8))) short short8v;
typedef __attribute__((ext_vector_type(4))) float float4v;
typedef __attribute__((ext_vector_type(2))) float float2v;

__device__ inline unsigned short f2bf(float f) {
    unsigned u = __float_as_uint(f);
    unsigned r = 0x7fffu + ((u >> 16) & 1u);
    return (unsigned short)((u + r) >> 16);
}
__device__ inline float bf2f(unsigned short u) {
    return __uint_as_float(((unsigned)u) << 16);
}

// ---------------- Kernel 1: prep (LN+concat+hist-zero) ∥ weights -------------
__global__ __launch_bounds__(256) void prep_weights_kernel(
    const float* __restrict__ nf, const float* __restrict__ frac,
    const float* __restrict__ lat, const int* __restrict__ n2g,
    const float* __restrict__ gamma, const float* __restrict__ beta,
    const float* __restrict__ Wq, const float* __restrict__ bq,
    const float* __restrict__ Wk, const float* __restrict__ bk,
    const float* __restrict__ Wv, const float* __restrict__ bv,
    const float* __restrict__ Wsk, const float* __restrict__ bsk,
    const float* __restrict__ We,
    unsigned short* __restrict__ xb, int* __restrict__ hist,
    unsigned short* __restrict__ wallT, float* __restrict__ bias_all,
    unsigned short* __restrict__ webt)
{
    if (blockIdx.x < PREP_BLOCKS) {
        // ---- prep: LayerNorm + concat -> bf16 x[N][160]; zero hist ----
        int wave = threadIdx.x >> 6;
        int lane = threadIdx.x & 63;
        int n = blockIdx.x * 4 + wave;
        if (n >= N_NODES) return;

        float v0 = nf[n * HIDDEN + lane];
        float v1 = nf[n * HIDDEN + 64 + lane];
        float s  = v0 + v1;
        float sq = v0 * v0 + v1 * v1;
        #pragma unroll
        for (int m = 1; m < 64; m <<= 1) {
            s  += __shfl_xor(s, m);
            sq += __shfl_xor(sq, m);
        }
        float mean = s * (1.0f / 128.0f);
        float var  = sq * (1.0f / 128.0f) - mean * mean;   // biased variance
        float inv  = rsqrtf(var + 1e-5f);

        xb[n * KPAD + lane]      = f2bf((v0 - mean) * inv * gamma[lane]      + beta[lane]);
        xb[n * KPAD + 64 + lane] = f2bf((v1 - mean) * inv * gamma[64 + lane] + beta[64 + lane]);
        if (lane < LATD) xb[n * KPAD + HIDDEN + lane]        = f2bf(lat[n2g[n] * LATD + lane]);
        if (lane < DISD) xb[n * KPAD + HIDDEN + LATD + lane] = f2bf(frac[n * DISD + lane]);
        if (lane >= 41)  xb[n * KPAD + 96 + lane] = 0;      // cols 137..159 zero-pad
        if (lane == 0)   hist[n] = 0;
    } else {
        // ---- weights: wallT bf16 (q,k,v,skip + fused Wqe) + biases + webt ----
        int idx = (blockIdx.x - PREP_BLOCKS) * 256 + threadIdx.x;
        if (idx >= WTOT) return;
        if (idx < NCOLS * KPAD) {
            int n = idx / KPAD, k = idx % KPAD;
            if (n < 1664) {
                float val = 0.0f;
                if (k < IN_DIM) {
                    if (n < 512)        val = Wq[(size_t)k * 512 + n];
                    else if (n < 1024)  val = Wk[(size_t)k * 512 + (n - 512)];
                    else if (n < 1536)  val = Wv[(size_t)k * 512 + (n - 1024)];
                    else                val = Wsk[(size_t)k * 128 + (n - 1536)];
                }
                wallT[idx] = f2bf(val);
                if (k == 0) {
                    float b;
                    if (n < 512)        b = bq[n];
                    else if (n < 1024)  b = bk[n - 512];
                    else if (n < 1536)  b = bv[n - 1024];
                    else                b = bsk[n - 1536];
                    bias_all[n] = b;
                }
            } else {
                int hj = n - 1664;                      // 0..239
                int h = hj / 60, j = hj % 60;
                float s = 0.0f;
                if (k < IN_DIM) {
                    #pragma unroll 4
                    for (int c = 0; c < 128; ++c)
                        s += Wq[(size_t)k * 512 + h * 128 + c] * We[(size_t)j * 512 + h * 128 + c];
                }
                wallT[idx] = f2bf(s);
                if (k == KPAD - 1) {
                    float b = 0.0f;
                    #pragma unroll 4
                    for (int c = 0; c < 128; ++c)
                        b += bq[h * 128 + c] * We[(size_t)j * 512 + h * 128 + c];
                    bias_all[n] = b;
                }
            }
        } else {
            int g = idx - NCOLS * KPAD;                 // webt[h][c][j], 4*128*64
            int h = g >> 13, c = (g >> 6) & 127, j = g & 63;
            float v = (j < 60) ? We[(size_t)j * 512 + h * 128 + c] : 0.0f;
            webt[g] = f2bf(v);
        }
    }
}

// ---------------- Kernel 2: histogram of dst --------------------------------
__global__ __launch_bounds__(256) void hist_kernel(
    const int* __restrict__ eidx, int* __restrict__ hist)
{
    int e = blockIdx.x * 256 + threadIdx.x;
    if (e < N_EDGES) atomicAdd(&hist[eidx[N_EDGES + e]], 1);
}

// ---------------- Kernel 3: exclusive scan (single block) -------------------
__global__ __launch_bounds__(1024) void scan_kernel(
    const int* __restrict__ hist, int* __restrict__ offsets, int* __restrict__ cursor)
{
    __shared__ int part[1024];
    const int t = threadIdx.x;
    const int base = t * 10;
    int loc[10];
    int s = 0;
    #pragma unroll
    for (int i = 0; i < 10; ++i) {
        int v = (base + i < N_NODES) ? hist[base + i] : 0;
        loc[i] = s; s += v;
    }
    part[t] = s;
    __syncthreads();
    for (int off = 1; off < 1024; off <<= 1) {
        int v = (t >= off) ? part[t - off] : 0;
        __syncthreads();
        part[t] += v;
        __syncthreads();
    }
    int pre = (t > 0) ? part[t - 1] : 0;
    #pragma unroll
    for (int i = 0; i < 10; ++i)
        if (base + i < N_NODES) {
            offsets[base + i] = pre + loc[i];
            cursor[base + i]  = pre + loc[i];
        }
    if (t == 1023) offsets[N_NODES] = part[1023];
}

// ---------------- Kernel 4: scatter ∥ MFMA GEMM ------------------------------
// Blocks [0, SCAT_BLOCKS): scatter edges into dst-sorted order (latency-bound,
// launched first so they run in the GEMM's shadow).
// Blocks [SCAT_BLOCKS, +15*157): GEMM xb[N,160] @ WallT^T. A staged in LDS;
// B fragments direct from global (wallT [col][k] = fragment layout, L2-res).
// q -> qbuf bf16 [N][512]; k -> fp8 e4m3, v -> bf16 packed kvb[node][h][384B];
// skip,qe -> sq f32 [N][384].
__global__ __launch_bounds__(256) void gemm_scatter_kernel(
    const unsigned short* __restrict__ xb, const unsigned short* __restrict__ wallT,
    const float* __restrict__ bias_all,
    const int* __restrict__ eidx, const float* __restrict__ fdiff,
    int* __restrict__ cursor, int* __restrict__ sorted_src,
    float* __restrict__ sorted_fd,
    float* __restrict__ sq, unsigned short* __restrict__ qbuf,
    unsigned char* __restrict__ kvb)
{
    __shared__ __align__(16) unsigned short Alds[64 * 168];

    if (blockIdx.x < SCAT_BLOCKS) {
        int e = blockIdx.x * 256 + threadIdx.x;
        if (e >= N_EDGES) return;
        int src = eidx[e];
        int dst = eidx[N_EDGES + e];
        int pos = atomicAdd(&cursor[dst], 1);
        sorted_src[pos] = src;
        sorted_fd[pos * 3 + 0] = fdiff[e * 3 + 0];
        sorted_fd[pos * 3 + 1] = fdiff[e * 3 + 1];
        sorted_fd[pos * 3 + 2] = fdiff[e * 3 + 2];
        return;
    }

    const int bx   = blockIdx.x - SCAT_BLOCKS;
    const int row0 = (bx / GEMM_BX) * 64;
    const int col0 = (bx % GEMM_BX) * 128;
    const int tid  = threadIdx.x;

    for (int i = tid; i < 64 * 20; i += 256) {       // A: 64 rows x 160 bf16
        int r = i / 20, c8 = (i % 20) * 8;
        uint4 v = make_uint4(0u, 0u, 0u, 0u);
        if (row0 + r < N_NODES)
            v = *reinterpret_cast<const uint4*>(&xb[(size_t)(row0 + r) * KPAD + c8]);
        *reinterpret_cast<uint4*>(&Alds[r * 168 + c8]) = v;
    }
    __syncthreads();

    const int l   = tid & 63;
    const int wid = tid >> 6;
    const int wr  = (wid >> 1) * 32;
    const int wc  = (wid & 1) * 64;
    const int lr  = l & 15;
    const int lk  = (l >> 4) * 8;

    float4v acc[2][4];
    #pragma unroll
    for (int tr = 0; tr < 2; ++tr)
        #pragma unroll
        for (int tc = 0; tc < 4; ++tc)
            acc[tr][tc] = (float4v){0.0f, 0.0f, 0.0f, 0.0f};

    #pragma unroll
    for (int ks = 0; ks < 5; ++ks) {
        short8v a[2], b[4];
        #pragma unroll
        for (int t = 0; t < 2; ++t)
            a[t] = *reinterpret_cast<const short8v*>(&Alds[(wr + t * 16 + lr) * 168 + ks * 32 + lk]);
        #pragma unroll
        for (int t = 0; t < 4; ++t)
            b[t] = *reinterpret_cast<const short8v*>(
                &wallT[(size_t)(col0 + wc + t * 16 + lr) * KPAD + ks * 32 + lk]);
        #pragma unroll
        for (int tr = 0; tr < 2; ++tr)
            #pragma unroll
            for (int tc = 0; tc < 4; ++tc)
                acc[tr][tc] = __builtin_amdgcn_mfma_f32_16x16x32_bf16(a[tr], b[tc], acc[tr][tc], 0, 0, 0);
    }

    #pragma unroll
    for (int tr = 0; tr < 2; ++tr) {
        #pragma unroll
        for (int tc = 0; tc < 4; ++tc) {
            const int col  = col0 + wc + tc * 16 + lr;
            const float bias = bias_all[col];
            #pragma unroll
            for (int j = 0; j < 4; ++j) {
                const int row = row0 + wr + tr * 16 + (l >> 4) * 4 + j;
                if (row < N_NODES) {
                    float val = acc[tr][tc][j] + bias;
                    if (col < 512) {                              // q -> bf16
                        qbuf[(size_t)row * 512 + col] = f2bf(val);
                    } else if (col < 1024) {                      // k -> fp8 e4m3
                        const int h = (col - 512) >> 7, ck = (col - 512) & 127;
                        int p = __builtin_amdgcn_cvt_pk_fp8_f32(val, val, 0, false);
                        kvb[((size_t)row * 4 + h) * 384 + ck] = (unsigned char)(p & 0xFF);
                    } else if (col < 1536) {                      // v -> bf16
                        const int h = (col - 1024) >> 7, cv = (col - 1024) & 127;
                        *reinterpret_cast<unsigned short*>(
                            kvb + ((size_t)row * 4 + h) * 384 + 128 + 2 * cv) = f2bf(val);
                    } else if (col < 1664) {                      // skip -> f32
                        sq[(size_t)row * 384 + (col - 1536)] = val;
                    } else if (col < NCOLS) {                     // qe -> f32
                        sq[(size_t)row * 384 + 128 + (col - 1664)] = val;
                    }
                }
            }
        }
    }
}

// ---------------- Kernel 5: per-node gather ----------------------------------
// Block = 1 node, wave = head, half-wave per edge, unroll 2.
// Per (src,h): one contiguous 384B region (k fp8 128B || v bf16 256B).
__global__ __launch_bounds__(256) void gather_kernel(
    const float* __restrict__ sq, const unsigned short* __restrict__ qbuf,
    const unsigned char* __restrict__ kvb,
    const int* __restrict__ offsets, const int* __restrict__ sorted_src,
    const float* __restrict__ sorted_fd,
    float* __restrict__ avbuf, unsigned short* __restrict__ aggbuf,
    float* __restrict__ sumwbuf)
{
    const int n    = blockIdx.x;
    const int h    = threadIdx.x >> 6;
    const int l    = threadIdx.x & 63;
    const int hl   = l & 31;
    const int half = l >> 5;
    const float TWO_PI = 6.283185307179586f;
    const float scale  = 0.08838834764831845f;   // 1/sqrt(128)

    const ushort4 qv = *reinterpret_cast<const ushort4*>(
        &qbuf[(size_t)n * 512 + h * 128 + 4 * hl]);
    const float q4x = bf2f(qv.x), q4y = bf2f(qv.y);
    const float q4z = bf2f(qv.z), q4w = bf2f(qv.w);
    const float qe_a = sq[(size_t)n * 384 + 128 + h * 60 + hl];  // j1 = hl (<60)
    const bool  v2ok = (hl < 28);                                // j2 = hl+32 < 60
    const float qe_b = v2ok ? sq[(size_t)n * 384 + 128 + h * 60 + hl + 32] : 0.0f;

    // emb slot 1: j1 = hl; slot 2: j2 = hl+32 (always cos)
    const int   jj1  = (hl < 30) ? hl : hl - 30;
    const int   sd1  = jj1 / 10;
    const float fc1  = TWO_PI * (float)(jj1 % 10);
    const bool  sin1 = (hl < 30);
    const int   jj2  = hl + 2;
    const int   sd2  = v2ok ? (jj2 / 10) : 0;
    const float fc2  = v2ok ? TWO_PI * (float)(jj2 % 10) : 0.0f;

    float ax = 0.f, ay = 0.f, az = 0.f, aw = 0.f;
    float agg1 = 0.f, agg2 = 0.f, sumw = 0.f;
    const int e0 = offsets[n], e1 = offsets[n + 1];

    for (int base = e0; base < e1; base += 4) {
        const int eA = base + half;
        const int eB = base + half + 2;
        const bool okA = (eA < e1), okB = (eB < e1);
        const int iA = okA ? eA : e0;
        const int iB = okB ? eB : e0;
        const int srcA = sorted_src[iA];
        const int srcB = sorted_src[iB];
        const float fdA1 = sorted_fd[iA * 3 + sd1];
        const float fdA2 = sorted_fd[iA * 3 + sd2];
        const float fdB1 = sorted_fd[iB * 3 + sd1];
        const float fdB2 = sorted_fd[iB * 3 + sd2];
        const unsigned char* pA = kvb + ((size_t)srcA * 4 + h) * 384;
        const unsigned char* pB = kvb + ((size_t)srcB * 4 + h) * 384;
        const unsigned kAu = *reinterpret_cast<const unsigned*>(pA + 4 * hl);
        const ushort4  vA  = *reinterpret_cast<const ushort4*>(pA + 128 + 8 * hl);
        const unsigned kBu = *reinterpret_cast<const unsigned*>(pB + 4 * hl);
        const ushort4  vB  = *reinterpret_cast<const ushort4*>(pB + 128 + 8 * hl);

        const float eA1 = sin1 ? __sinf(fdA1 * fc1) : __cosf(fdA1 * fc1);
        const float eA2 = __cosf(fdA2 * fc2);
        const float eB1 = sin1 ? __sinf(fdB1 * fc1) : __cosf(fdB1 * fc1);
        const float eB2 = __cosf(fdB2 * fc2);

        const float2v kA01 = __builtin_amdgcn_cvt_pk_f32_fp8(kAu, false);
        const float2v kA23 = __builtin_amdgcn_cvt_pk_f32_fp8(kAu, true);
        const float2v kB01 = __builtin_amdgcn_cvt_pk_f32_fp8(kBu, false);
        const float2v kB23 = __builtin_amdgcn_cvt_pk_f32_fp8(kBu, true);

        float pAs = q4x * kA01[0] + q4y * kA01[1]
                  + q4z * kA23[0] + q4w * kA23[1]
                  + eA1 * qe_a + eA2 * qe_b;
        float pBs = q4x * kB01[0] + q4y * kB01[1]
                  + q4z * kB23[0] + q4w * kB23[1]
                  + eB1 * qe_a + eB2 * qe_b;
        #pragma unroll
        for (int m = 1; m <= 16; m <<= 1) {
            pAs += __shfl_xor(pAs, m);
            pBs += __shfl_xor(pBs, m);
        }
        const float wA = okA ? __expf(pAs * scale) : 0.0f;
        const float wB = okB ? __expf(pBs * scale) : 0.0f;
        sumw += wA + wB;
        ax += wA * bf2f(vA.x) + wB * bf2f(vB.x);
        ay += wA * bf2f(vA.y) + wB * bf2f(vB.y);
        az += wA * bf2f(vA.z) + wB * bf2f(vB.z);
        aw += wA * bf2f(vA.w) + wB * bf2f(vB.w);
        agg1 += wA * eA1 + wB * eB1;
        if (v2ok) agg2 += wA * eA2 + wB * eB2;
    }

    // combine the two halves
    sumw += __shfl_xor(sumw, 32);
    ax += __shfl_xor(ax, 32);  ay += __shfl_xor(ay, 32);
    az += __shfl_xor(az, 32);  aw += __shfl_xor(aw, 32);
    agg1 += __shfl_xor(agg1, 32);
    agg2 += __shfl_xor(agg2, 32);

    if (half == 0) {
        float4 r;
        r.x = ax; r.y = ay; r.z = az; r.w = aw;
        *reinterpret_cast<float4*>(&avbuf[(size_t)n * 512 + h * 128 + 4 * hl]) = r;
        aggbuf[n * 256 + h * 64 + hl]      = f2bf(agg1);           // j = hl
        aggbuf[n * 256 + h * 64 + 32 + hl] = f2bf(agg2);           // j = hl+32
        if (hl == 0) sumwbuf[n * 4 + h] = sumw;
    }
}

// ---------------- Kernel 6: corr MFMA — avbuf += aggemb @ Webt ---------------
// Block = 32 nodes, 4 waves (wave h = head h). A: aggemb [32][256] bf16;
// B direct from global webt[h][128][64] (L2-resident, 64 KB).
__global__ __launch_bounds__(256) void corr_kernel(
    const unsigned short* __restrict__ webt, const unsigned short* __restrict__ aggbuf,
    float* __restrict__ avbuf)
{
    __shared__ __align__(16) unsigned short Alds[32 * 264];
    const int node0 = blockIdx.x * 32;
    const int tid = threadIdx.x;

    for (int i = tid; i < 32 * 32; i += 256) {       // A: 1024 uint4
        int r = i >> 5, c8 = (i & 31) * 8;
        uint4 v = make_uint4(0u, 0u, 0u, 0u);
        if (node0 + r < N_NODES)
            v = *reinterpret_cast<const uint4*>(&aggbuf[(size_t)(node0 + r) * 256 + c8]);
        *reinterpret_cast<uint4*>(&Alds[r * 264 + c8]) = v;
    }
    __syncthreads();

    const int l  = tid & 63;
    const int h  = tid >> 6;
    const int lr = l & 15;
    const int lk = (l >> 4) * 8;

    float4v acc[2][8];
    #pragma unroll
    for (int m = 0; m < 2; ++m)
        #pragma unroll
        for (int nn = 0; nn < 8; ++nn)
            acc[m][nn] = (float4v){0.0f, 0.0f, 0.0f, 0.0f};

    #pragma unroll
    for (int ks = 0; ks < 2; ++ks) {
        short8v a[2], b[8];
        #pragma unroll
        for (int m = 0; m < 2; ++m)
            a[m] = *reinterpret_cast<const short8v*>(
                &Alds[(m * 16 + lr) * 264 + h * 64 + ks * 32 + lk]);
        #pragma unroll
        for (int nn = 0; nn < 8; ++nn)
            b[nn] = *reinterpret_cast<const short8v*>(
                &webt[(size_t)(h * 128 + nn * 16 + lr) * 64 + ks * 32 + lk]);
        #pragma unroll
        for (int m = 0; m < 2; ++m)
            #pragma unroll
            for (int nn = 0; nn < 8; ++nn)
                acc[m][nn] = __builtin_amdgcn_mfma_f32_16x16x32_bf16(a[m], b[nn], acc[m][nn], 0, 0, 0);
    }

    #pragma unroll
    for (int m = 0; m < 2; ++m) {
        #pragma unroll
        for (int nn = 0; nn < 8; ++nn) {
            const int col = h * 128 + nn * 16 + lr;
            #pragma unroll
            for (int j = 0; j < 4; ++j) {
                const int rowi = node0 + m * 16 + (l >> 4) * 4 + j;
                if (rowi < N_NODES) {
                    float* p = &avbuf[(size_t)rowi * 512 + col];
                    *p += acc[m][nn][j];
                }
            }
        }
    }
}

// ---------------- Kernel 7: finalize ----------------------------------------
__global__ __launch_bounds__(256) void finalize_kernel(
    const float* __restrict__ avbuf, const float* __restrict__ sumwbuf,
    const float* __restrict__ sq, const float* __restrict__ nf,
    float* __restrict__ out)
{
    int idx = blockIdx.x * 256 + threadIdx.x;
    if (idx >= N_NODES * CHAN) return;
    int n = idx >> 7, c = idx & 127;
    float z = 0.0f;
    #pragma unroll
    for (int h = 0; h < NHEAD; ++h)
        z += avbuf[(size_t)n * 512 + h * 128 + c] / (sumwbuf[n * 4 + h] + 1e-16f);
    z = 0.25f * z + sq[(size_t)n * 384 + c];        // head mean + skip
    float si = z / (1.0f + __expf(-z));             // silu
    out[idx] = nf[idx] + si;
}

// ---------------- launcher ---------------------------------------------------
extern "C" void kernel_launch(void* const* d_in, const int* in_sizes, int n_in,
                              void* d_out, int out_size, void* d_ws, size_t ws_size,
                              hipStream_t stream)
{
    const float* nf    = (const float*)d_in[0];
    const float* frac  = (const float*)d_in[1];
    const float* lat   = (const float*)d_in[2];
    const int*   eidx  = (const int*)  d_in[3];
    const int*   n2g   = (const int*)  d_in[4];
    const float* fdiff = (const float*)d_in[5];
    const float* gamma = (const float*)d_in[6];
    const float* beta  = (const float*)d_in[7];
    const float* Wq    = (const float*)d_in[8];
    const float* bq    = (const float*)d_in[9];
    const float* Wk    = (const float*)d_in[10];
    const float* bk    = (const float*)d_in[11];
    const float* Wv    = (const float*)d_in[12];
    const float* bv    = (const float*)d_in[13];
    const float* We    = (const float*)d_in[14];
    const float* Wsk   = (const float*)d_in[15];
    const float* bsk   = (const float*)d_in[16];
    float* out = (float*)d_out;

    // workspace layout
    float* sq        = (float*)d_ws;                               // N*384 (skip,qe)
    float* avbuf     = sq + (size_t)N_NODES * 384;                 // N*512
    float* sumwbuf   = avbuf + (size_t)N_NODES * 512;              // N*4
    float* bias_all  = sumwbuf + (size_t)N_NODES * 4;              // 1920
    float* sorted_fd = bias_all + NPAD;                            // E*3
    unsigned short* xb     = (unsigned short*)(sorted_fd + (size_t)N_EDGES * 3); // N*160
    unsigned short* wallT  = xb + (size_t)N_NODES * KPAD;          // 1920*160
    unsigned short* webt   = wallT + (size_t)NPAD * KPAD;          // 4*128*64
    unsigned short* aggbuf = webt + 4 * 128 * 64;                  // N*256
    unsigned short* qbuf   = aggbuf + (size_t)N_NODES * 256;       // N*512
    unsigned char*  kvb    = (unsigned char*)(qbuf + (size_t)N_NODES * 512); // N*4*384 bytes
    int* hist       = (int*)(kvb + (size_t)N_NODES * 4 * 384);     // N
    int* offsets    = hist + N_NODES;                              // N+1
    int* cursor     = offsets + N_NODES + 1;                       // N
    int* sorted_src = cursor + N_NODES;                            // E

    prep_weights_kernel<<<PREP_BLOCKS + WBLOCKS, 256, 0, stream>>>(
        nf, frac, lat, n2g, gamma, beta,
        Wq, bq, Wk, bk, Wv, bv, Wsk, bsk, We,
        xb, hist, wallT, bias_all, webt);

    hist_kernel<<<(N_EDGES + 255) / 256, 256, 0, stream>>>(eidx, hist);
    scan_kernel<<<1, 1024, 0, stream>>>(hist, offsets, cursor);

    gemm_scatter_kernel<<<SCAT_BLOCKS + GEMM_BX * GEMM_BY, 256, 0, stream>>>(
        xb, wallT, bias_all, eidx, fdiff, cursor, sorted_src, sorted_fd,
        sq, qbuf, kvb);

    gather_kernel<<<N_NODES, 256, 0, stream>>>(
        sq, qbuf, kvb, offsets, sorted_src, sorted_fd, avbuf, aggbuf, sumwbuf);

    corr_kernel<<<(N_NODES + 31) / 32, 256, 0, stream>>>(webt, aggbuf, avbuf);

    finalize_kernel<<<(N_NODES * CHAN + 255) / 256, 256, 0, stream>>>(
        avbuf, sumwbuf, sq, nf, out);
}

// Round 10
// 141.107 us; speedup vs baseline: 1.3705x; 1.0509x over previous
//
#include <hip/hip_runtime.h>
#include <math.h>

#define N_NODES 10000
#define N_EDGES 100000
#define HIDDEN  128
#define NHEAD   4
#define CHAN    128
#define IN_DIM  137      // 128 + 6 + 3
#define KPAD    160      // padded K for MFMA
#define NCOLS   1904     // 512*3 + 128 + 240
#define NPAD    1920     // padded to 15*128
#define LATD    6
#define DISD    3

#define PREP_BLOCKS 2500                       // 4 nodes/block
#define TRANS_TILES 26                         // 1664 cols / 64
#define WQE_BLOCKS  150                        // 240*160 / 256
#define WEBT_BLOCKS 128                        // 4*128*64 / 256

#define SCAT_BLOCKS ((N_EDGES + 255) / 256)    // 391
#define GEMM_BX 15
#define GEMM_BY ((N_NODES + 63) / 64)          // 157

typedef __attribute__((ext_vector_type(8))) short short8v;
typedef __attribute__((ext_vector_type(4))) float float4v;
typedef __attribute__((ext_vector_type(2))) float float2v;

__device__ inline unsigned short f2bf(float f) {
    unsigned u = __float_as_uint(f);
    unsigned r = 0x7fffu + ((u >> 16) & 1u);
    return (unsigned short)((u + r) >> 16);
}
__device__ inline float bf2f(unsigned short u) {
    return __uint_as_float(((unsigned)u) << 16);
}

// ---------------- Kernel 1: prep ∥ W-transpose ∥ wqe ∥ webt -------------------
__global__ __launch_bounds__(256) void prep_weights_kernel(
    const float* __restrict__ nf, const float* __restrict__ frac,
    const float* __restrict__ lat, const int* __restrict__ n2g,
    const float* __restrict__ gamma, const float* __restrict__ beta,
    const float* __restrict__ Wq, const float* __restrict__ bq,
    const float* __restrict__ Wk, const float* __restrict__ bk,
    const float* __restrict__ Wv, const float* __restrict__ bv,
    const float* __restrict__ Wsk, const float* __restrict__ bsk,
    const float* __restrict__ We,
    unsigned short* __restrict__ xb, int* __restrict__ hist,
    unsigned short* __restrict__ wallT, float* __restrict__ bias_all,
    unsigned short* __restrict__ webt)
{
    __shared__ __align__(16) unsigned short Tlds[64 * 168];
    const int tid = threadIdx.x;

    if (blockIdx.x < PREP_BLOCKS) {
        // ---- prep: LayerNorm + concat -> bf16 x[N][160]; zero hist ----
        int wave = tid >> 6;
        int lane = tid & 63;
        int n = blockIdx.x * 4 + wave;
        if (n >= N_NODES) return;

        float v0 = nf[n * HIDDEN + lane];
        float v1 = nf[n * HIDDEN + 64 + lane];
        float s  = v0 + v1;
        float sq = v0 * v0 + v1 * v1;
        #pragma unroll
        for (int m = 1; m < 64; m <<= 1) {
            s  += __shfl_xor(s, m);
            sq += __shfl_xor(sq, m);
        }
        float mean = s * (1.0f / 128.0f);
        float var  = sq * (1.0f / 128.0f) - mean * mean;   // biased variance
        float inv  = rsqrtf(var + 1e-5f);

        xb[n * KPAD + lane]      = f2bf((v0 - mean) * inv * gamma[lane]      + beta[lane]);
        xb[n * KPAD + 64 + lane] = f2bf((v1 - mean) * inv * gamma[64 + lane] + beta[64 + lane]);
        if (lane < LATD) xb[n * KPAD + HIDDEN + lane]        = f2bf(lat[n2g[n] * LATD + lane]);
        if (lane < DISD) xb[n * KPAD + HIDDEN + LATD + lane] = f2bf(frac[n * DISD + lane]);
        if (lane >= 41)  xb[n * KPAD + 96 + lane] = 0;      // cols 137..159 zero-pad
        if (lane == 0)   hist[n] = 0;
    } else if (blockIdx.x < PREP_BLOCKS + TRANS_TILES) {
        // ---- LDS-tiled transpose: wallT[n][k] = W[k][n], 64 cols/tile ----
        const int n0 = (blockIdx.x - PREP_BLOCKS) * 64;
        for (int i = tid; i < 160 * 64; i += 256) {
            const int k = i >> 6, n = i & 63;
            const int col = n0 + n;
            float val = 0.0f;
            if (k < IN_DIM) {
                if (col < 512)        val = Wq[(size_t)k * 512 + col];
                else if (col < 1024)  val = Wk[(size_t)k * 512 + (col - 512)];
                else if (col < 1536)  val = Wv[(size_t)k * 512 + (col - 1024)];
                else                  val = Wsk[(size_t)k * 128 + (col - 1536)];
            }
            Tlds[n * 168 + k] = f2bf(val);
        }
        __syncthreads();
        for (int i = tid; i < 64 * 20; i += 256) {           // fully coalesced
            const int n = i / 20, c8 = (i % 20) * 8;
            *reinterpret_cast<uint4*>(&wallT[(size_t)(n0 + n) * KPAD + c8]) =
                *reinterpret_cast<const uint4*>(&Tlds[n * 168 + c8]);
        }
        if (tid < 64) {
            const int col = n0 + tid;
            float b;
            if (col < 512)        b = bq[col];
            else if (col < 1024)  b = bk[col - 512];
            else if (col < 1536)  b = bv[col - 1024];
            else                  b = bsk[col - 1536];
            bias_all[col] = b;
        }
    } else if (blockIdx.x < PREP_BLOCKS + TRANS_TILES + WQE_BLOCKS) {
        // ---- wqe: fused Wqe = Wq (x) We^T per head -> wallT cols 1664.. ----
        int idx = (blockIdx.x - PREP_BLOCKS - TRANS_TILES) * 256 + tid;
        if (idx >= 240 * KPAD) return;
        int hj = idx / KPAD, k = idx % KPAD;
        int h = hj / 60, j = hj % 60;
        float s = 0.0f;
        if (k < IN_DIM) {
            #pragma unroll 4
            for (int c = 0; c < 128; ++c)
                s += Wq[(size_t)k * 512 + h * 128 + c] * We[(size_t)j * 512 + h * 128 + c];
        }
        wallT[(size_t)(1664 + hj) * KPAD + k] = f2bf(s);
        if (k == KPAD - 1) {
            float b = 0.0f;
            #pragma unroll 4
            for (int c = 0; c < 128; ++c)
                b += bq[h * 128 + c] * We[(size_t)j * 512 + h * 128 + c];
            bias_all[1664 + hj] = b;
        }
    } else {
        // ---- webt[h][c][j] bf16 for corr ----
        int g = (blockIdx.x - PREP_BLOCKS - TRANS_TILES - WQE_BLOCKS) * 256 + tid;
        if (g >= 4 * 128 * 64) return;
        int h = g >> 13, c = (g >> 6) & 127, j = g & 63;
        float v = (j < 60) ? We[(size_t)j * 512 + h * 128 + c] : 0.0f;
        webt[g] = f2bf(v);
    }
}

// ---------------- Kernel 2: histogram of dst --------------------------------
__global__ __launch_bounds__(256) void hist_kernel(
    const int* __restrict__ eidx, int* __restrict__ hist)
{
    int e = blockIdx.x * 256 + threadIdx.x;
    if (e < N_EDGES) atomicAdd(&hist[eidx[N_EDGES + e]], 1);
}

// ---------------- Kernel 3: exclusive scan (single block) -------------------
__global__ __launch_bounds__(1024) void scan_kernel(
    const int* __restrict__ hist, int* __restrict__ offsets, int* __restrict__ cursor)
{
    __shared__ int part[1024];
    const int t = threadIdx.x;
    const int base = t * 10;
    int loc[10];
    int s = 0;
    #pragma unroll
    for (int i = 0; i < 10; ++i) {
        int v = (base + i < N_NODES) ? hist[base + i] : 0;
        loc[i] = s; s += v;
    }
    part[t] = s;
    __syncthreads();
    for (int off = 1; off < 1024; off <<= 1) {
        int v = (t >= off) ? part[t - off] : 0;
        __syncthreads();
        part[t] += v;
        __syncthreads();
    }
    int pre = (t > 0) ? part[t - 1] : 0;
    #pragma unroll
    for (int i = 0; i < 10; ++i)
        if (base + i < N_NODES) {
            offsets[base + i] = pre + loc[i];
            cursor[base + i]  = pre + loc[i];
        }
    if (t == 1023) offsets[N_NODES] = part[1023];
}

// ---------------- Kernel 4: scatter ∥ MFMA GEMM ------------------------------
// q -> qbuf bf16 [N][512]; k,v -> fp8 e4m3 packed kvb[node][h][256B];
// skip,qe -> sq f32 [N][384].
__global__ __launch_bounds__(256) void gemm_scatter_kernel(
    const unsigned short* __restrict__ xb, const unsigned short* __restrict__ wallT,
    const float* __restrict__ bias_all,
    const int* __restrict__ eidx, const float* __restrict__ fdiff,
    int* __restrict__ cursor, int* __restrict__ sorted_src,
    float* __restrict__ sorted_fd,
    float* __restrict__ sq, unsigned short* __restrict__ qbuf,
    unsigned char* __restrict__ kvb)
{
    __shared__ __align__(16) unsigned short Alds[64 * 168];

    if (blockIdx.x < SCAT_BLOCKS) {
        int e = blockIdx.x * 256 + threadIdx.x;
        if (e >= N_EDGES) return;
        int src = eidx[e];
        int dst = eidx[N_EDGES + e];
        int pos = atomicAdd(&cursor[dst], 1);
        sorted_src[pos] = src;
        sorted_fd[pos * 3 + 0] = fdiff[e * 3 + 0];
        sorted_fd[pos * 3 + 1] = fdiff[e * 3 + 1];
        sorted_fd[pos * 3 + 2] = fdiff[e * 3 + 2];
        return;
    }

    const int bx   = blockIdx.x - SCAT_BLOCKS;
    const int row0 = (bx / GEMM_BX) * 64;
    const int col0 = (bx % GEMM_BX) * 128;
    const int tid  = threadIdx.x;

    for (int i = tid; i < 64 * 20; i += 256) {       // A: 64 rows x 160 bf16
        int r = i / 20, c8 = (i % 20) * 8;
        uint4 v = make_uint4(0u, 0u, 0u, 0u);
        if (row0 + r < N_NODES)
            v = *reinterpret_cast<const uint4*>(&xb[(size_t)(row0 + r) * KPAD + c8]);
        *reinterpret_cast<uint4*>(&Alds[r * 168 + c8]) = v;
    }
    __syncthreads();

    const int l   = tid & 63;
    const int wid = tid >> 6;
    const int wr  = (wid >> 1) * 32;
    const int wc  = (wid & 1) * 64;
    const int lr  = l & 15;
    const int lk  = (l >> 4) * 8;

    float4v acc[2][4];
    #pragma unroll
    for (int tr = 0; tr < 2; ++tr)
        #pragma unroll
        for (int tc = 0; tc < 4; ++tc)
            acc[tr][tc] = (float4v){0.0f, 0.0f, 0.0f, 0.0f};

    #pragma unroll
    for (int ks = 0; ks < 5; ++ks) {
        short8v a[2], b[4];
        #pragma unroll
        for (int t = 0; t < 2; ++t)
            a[t] = *reinterpret_cast<const short8v*>(&Alds[(wr + t * 16 + lr) * 168 + ks * 32 + lk]);
        #pragma unroll
        for (int t = 0; t < 4; ++t)
            b[t] = *reinterpret_cast<const short8v*>(
                &wallT[(size_t)(col0 + wc + t * 16 + lr) * KPAD + ks * 32 + lk]);
        #pragma unroll
        for (int tr = 0; tr < 2; ++tr)
            #pragma unroll
            for (int tc = 0; tc < 4; ++tc)
                acc[tr][tc] = __builtin_amdgcn_mfma_f32_16x16x32_bf16(a[tr], b[tc], acc[tr][tc], 0, 0, 0);
    }

    #pragma unroll
    for (int tr = 0; tr < 2; ++tr) {
        #pragma unroll
        for (int tc = 0; tc < 4; ++tc) {
            const int col  = col0 + wc + tc * 16 + lr;
            const float bias = bias_all[col];
            #pragma unroll
            for (int j = 0; j < 4; ++j) {
                const int row = row0 + wr + tr * 16 + (l >> 4) * 4 + j;
                if (row < N_NODES) {
                    float val = acc[tr][tc][j] + bias;
                    if (col < 512) {                              // q -> bf16
                        qbuf[(size_t)row * 512 + col] = f2bf(val);
                    } else if (col < 1024) {                      // k -> fp8 e4m3
                        const int h = (col - 512) >> 7, ck = (col - 512) & 127;
                        int p = __builtin_amdgcn_cvt_pk_fp8_f32(val, val, 0, false);
                        kvb[((size_t)row * 4 + h) * 256 + ck] = (unsigned char)(p & 0xFF);
                    } else if (col < 1536) {                      // v -> fp8 e4m3
                        const int h = (col - 1024) >> 7, cv = (col - 1024) & 127;
                        int p = __builtin_amdgcn_cvt_pk_fp8_f32(val, val, 0, false);
                        kvb[((size_t)row * 4 + h) * 256 + 128 + cv] = (unsigned char)(p & 0xFF);
                    } else if (col < 1664) {                      // skip -> f32
                        sq[(size_t)row * 384 + (col - 1536)] = val;
                    } else if (col < NCOLS) {                     // qe -> f32
                        sq[(size_t)row * 384 + 128 + (col - 1664)] = val;
                    }
                }
            }
        }
    }
}

// ---------------- Kernel 5: per-node gather ----------------------------------
// Block = 1 node, wave = head, half-wave per edge, unroll 2.
// Per (src,h): one contiguous 256B region (k fp8 128B || v fp8 128B).
__global__ __launch_bounds__(256) void gather_kernel(
    const float* __restrict__ sq, const unsigned short* __restrict__ qbuf,
    const unsigned char* __restrict__ kvb,
    const int* __restrict__ offsets, const int* __restrict__ sorted_src,
    const float* __restrict__ sorted_fd,
    float* __restrict__ avbuf, unsigned short* __restrict__ aggbuf,
    float* __restrict__ sumwbuf)
{
    const int n    = blockIdx.x;
    const int h    = threadIdx.x >> 6;
    const int l    = threadIdx.x & 63;
    const int hl   = l & 31;
    const int half = l >> 5;
    const float TWO_PI = 6.283185307179586f;
    const float scale  = 0.08838834764831845f;   // 1/sqrt(128)

    const ushort4 qv = *reinterpret_cast<const ushort4*>(
        &qbuf[(size_t)n * 512 + h * 128 + 4 * hl]);
    const float q4x = bf2f(qv.x), q4y = bf2f(qv.y);
    const float q4z = bf2f(qv.z), q4w = bf2f(qv.w);
    const float qe_a = sq[(size_t)n * 384 + 128 + h * 60 + hl];  // j1 = hl (<60)
    const bool  v2ok = (hl < 28);                                // j2 = hl+32 < 60
    const float qe_b = v2ok ? sq[(size_t)n * 384 + 128 + h * 60 + hl + 32] : 0.0f;

    // emb slot 1: j1 = hl; slot 2: j2 = hl+32 (always cos)
    const int   jj1  = (hl < 30) ? hl : hl - 30;
    const int   sd1  = jj1 / 10;
    const float fc1  = TWO_PI * (float)(jj1 % 10);
    const bool  sin1 = (hl < 30);
    const int   jj2  = hl + 2;
    const int   sd2  = v2ok ? (jj2 / 10) : 0;
    const float fc2  = v2ok ? TWO_PI * (float)(jj2 % 10) : 0.0f;

    float ax = 0.f, ay = 0.f, az = 0.f, aw = 0.f;
    float agg1 = 0.f, agg2 = 0.f, sumw = 0.f;
    const int e0 = offsets[n], e1 = offsets[n + 1];

    for (int base = e0; base < e1; base += 4) {
        const int eA = base + half;
        const int eB = base + half + 2;
        const bool okA = (eA < e1), okB = (eB < e1);
        const int iA = okA ? eA : e0;
        const int iB = okB ? eB : e0;
        const int srcA = sorted_src[iA];
        const int srcB = sorted_src[iB];
        const float fdA1 = sorted_fd[iA * 3 + sd1];
        const float fdA2 = sorted_fd[iA * 3 + sd2];
        const float fdB1 = sorted_fd[iB * 3 + sd1];
        const float fdB2 = sorted_fd[iB * 3 + sd2];
        const unsigned char* pA = kvb + ((size_t)srcA * 4 + h) * 256;
        const unsigned char* pB = kvb + ((size_t)srcB * 4 + h) * 256;
        const unsigned kAu = *reinterpret_cast<const unsigned*>(pA + 4 * hl);
        const unsigned vAu = *reinterpret_cast<const unsigned*>(pA + 128 + 4 * hl);
        const unsigned kBu = *reinterpret_cast<const unsigned*>(pB + 4 * hl);
        const unsigned vBu = *reinterpret_cast<const unsigned*>(pB + 128 + 4 * hl);

        const float eA1 = sin1 ? __sinf(fdA1 * fc1) : __cosf(fdA1 * fc1);
        const float eA2 = __cosf(fdA2 * fc2);
        const float eB1 = sin1 ? __sinf(fdB1 * fc1) : __cosf(fdB1 * fc1);
        const float eB2 = __cosf(fdB2 * fc2);

        const float2v kA01 = __builtin_amdgcn_cvt_pk_f32_fp8(kAu, false);
        const float2v kA23 = __builtin_amdgcn_cvt_pk_f32_fp8(kAu, true);
        const float2v kB01 = __builtin_amdgcn_cvt_pk_f32_fp8(kBu, false);
        const float2v kB23 = __builtin_amdgcn_cvt_pk_f32_fp8(kBu, true);

        float pAs = q4x * kA01[0] + q4y * kA01[1]
                  + q4z * kA23[0] + q4w * kA23[1]
                  + eA1 * qe_a + eA2 * qe_b;
        float pBs = q4x * kB01[0] + q4y * kB01[1]
                  + q4z * kB23[0] + q4w * kB23[1]
                  + eB1 * qe_a + eB2 * qe_b;
        #pragma unroll
        for (int m = 1; m <= 16; m <<= 1) {
            pAs += __shfl_xor(pAs, m);
            pBs += __shfl_xor(pBs, m);
        }
        const float wA = okA ? __expf(pAs * scale) : 0.0f;
        const float wB = okB ? __expf(pBs * scale) : 0.0f;
        sumw += wA + wB;

        const float2v vA01 = __builtin_amdgcn_cvt_pk_f32_fp8(vAu, false);
        const float2v vA23 = __builtin_amdgcn_cvt_pk_f32_fp8(vAu, true);
        const float2v vB01 = __builtin_amdgcn_cvt_pk_f32_fp8(vBu, false);
        const float2v vB23 = __builtin_amdgcn_cvt_pk_f32_fp8(vBu, true);
        ax += wA * vA01[0] + wB * vB01[0];
        ay += wA * vA01[1] + wB * vB01[1];
        az += wA * vA23[0] + wB * vB23[0];
        aw += wA * vA23[1] + wB * vB23[1];
        agg1 += wA * eA1 + wB * eB1;
        if (v2ok) agg2 += wA * eA2 + wB * eB2;
    }

    // combine the two halves
    sumw += __shfl_xor(sumw, 32);
    ax += __shfl_xor(ax, 32);  ay += __shfl_xor(ay, 32);
    az += __shfl_xor(az, 32);  aw += __shfl_xor(aw, 32);
    agg1 += __shfl_xor(agg1, 32);
    agg2 += __shfl_xor(agg2, 32);

    if (half == 0) {
        float4 r;
        r.x = ax; r.y = ay; r.z = az; r.w = aw;
        *reinterpret_cast<float4*>(&avbuf[(size_t)n * 512 + h * 128 + 4 * hl]) = r;
        aggbuf[n * 256 + h * 64 + hl]      = f2bf(agg1);           // j = hl
        aggbuf[n * 256 + h * 64 + 32 + hl] = f2bf(agg2);           // j = hl+32
        if (hl == 0) sumwbuf[n * 4 + h] = sumw;
    }
}

// ---------------- Kernel 6: corr MFMA — avbuf += aggemb @ Webt ---------------
__global__ __launch_bounds__(256) void corr_kernel(
    const unsigned short* __restrict__ webt, const unsigned short* __restrict__ aggbuf,
    float* __restrict__ avbuf)
{
    __shared__ __align__(16) unsigned short Alds[32 * 264];
    const int node0 = blockIdx.x * 32;
    const int tid = threadIdx.x;

    for (int i = tid; i < 32 * 32; i += 256) {       // A: 1024 uint4
        int r = i >> 5, c8 = (i & 31) * 8;
        uint4 v = make_uint4(0u, 0u, 0u, 0u);
        if (node0 + r < N_NODES)
            v = *reinterpret_cast<const uint4*>(&aggbuf[(size_t)(node0 + r) * 256 + c8]);
        *reinterpret_cast<uint4*>(&Alds[r * 264 + c8]) = v;
    }
    __syncthreads();

    const int l  = tid & 63;
    const int h  = tid >> 6;
    const int lr = l & 15;
    const int lk = (l >> 4) * 8;

    float4v acc[2][8];
    #pragma unroll
    for (int m = 0; m < 2; ++m)
        #pragma unroll
        for (int nn = 0; nn < 8; ++nn)
            acc[m][nn] = (float4v){0.0f, 0.0f, 0.0f, 0.0f};

    #pragma unroll
    for (int ks = 0; ks < 2; ++ks) {
        short8v a[2], b[8];
        #pragma unroll
        for (int m = 0; m < 2; ++m)
            a[m] = *reinterpret_cast<const short8v*>(
                &Alds[(m * 16 + lr) * 264 + h * 64 + ks * 32 + lk]);
        #pragma unroll
        for (int nn = 0; nn < 8; ++nn)
            b[nn] = *reinterpret_cast<const short8v*>(
                &webt[(size_t)(h * 128 + nn * 16 + lr) * 64 + ks * 32 + lk]);
        #pragma unroll
        for (int m = 0; m < 2; ++m)
            #pragma unroll
            for (int nn = 0; nn < 8; ++nn)
                acc[m][nn] = __builtin_amdgcn_mfma_f32_16x16x32_bf16(a[m], b[nn], acc[m][nn], 0, 0, 0);
    }

    #pragma unroll
    for (int m = 0; m < 2; ++m) {
        #pragma unroll
        for (int nn = 0; nn < 8; ++nn) {
            const int col = h * 128 + nn * 16 + lr;
            #pragma unroll
            for (int j = 0; j < 4; ++j) {
                const int rowi = node0 + m * 16 + (l >> 4) * 4 + j;
                if (rowi < N_NODES) {
                    float* p = &avbuf[(size_t)rowi * 512 + col];
                    *p += acc[m][nn][j];
                }
            }
        }
    }
}

// ---------------- Kernel 7: finalize ----------------------------------------
__global__ __launch_bounds__(256) void finalize_kernel(
    const float* __restrict__ avbuf, const float* __restrict__ sumwbuf,
    const float* __restrict__ sq, const float* __restrict__ nf,
    float* __restrict__ out)
{
    int idx = blockIdx.x * 256 + threadIdx.x;
    if (idx >= N_NODES * CHAN) return;
    int n = idx >> 7, c = idx & 127;
    float z = 0.0f;
    #pragma unroll
    for (int h = 0; h < NHEAD; ++h)
        z += avbuf[(size_t)n * 512 + h * 128 + c] / (sumwbuf[n * 4 + h] + 1e-16f);
    z = 0.25f * z + sq[(size_t)n * 384 + c];        // head mean + skip
    float si = z / (1.0f + __expf(-z));             // silu
    out[idx] = nf[idx] + si;
}

// ---------------- launcher ---------------------------------------------------
extern "C" void kernel_launch(void* const* d_in, const int* in_sizes, int n_in,
                              void* d_out, int out_size, void* d_ws, size_t ws_size,
                              hipStream_t stream)
{
    const float* nf    = (const float*)d_in[0];
    const float* frac  = (const float*)d_in[1];
    const float* lat   = (const float*)d_in[2];
    const int*   eidx  = (const int*)  d_in[3];
    const int*   n2g   = (const int*)  d_in[4];
    const float* fdiff = (const float*)d_in[5];
    const float* gamma = (const float*)d_in[6];
    const float* beta  = (const float*)d_in[7];
    const float* Wq    = (const float*)d_in[8];
    const float* bq    = (const float*)d_in[9];
    const float* Wk    = (const float*)d_in[10];
    const float* bk    = (const float*)d_in[11];
    const float* Wv    = (const float*)d_in[12];
    const float* bv    = (const float*)d_in[13];
    const float* We    = (const float*)d_in[14];
    const float* Wsk   = (const float*)d_in[15];
    const float* bsk   = (const float*)d_in[16];
    float* out = (float*)d_out;

    // workspace layout
    float* sq        = (float*)d_ws;                               // N*384 (skip,qe)
    float* avbuf     = sq + (size_t)N_NODES * 384;                 // N*512
    float* sumwbuf   = avbuf + (size_t)N_NODES * 512;              // N*4
    float* bias_all  = sumwbuf + (size_t)N_NODES * 4;              // 1920
    float* sorted_fd = bias_all + NPAD;                            // E*3
    unsigned short* xb     = (unsigned short*)(sorted_fd + (size_t)N_EDGES * 3); // N*160
    unsigned short* wallT  = xb + (size_t)N_NODES * KPAD;          // 1920*160
    unsigned short* webt   = wallT + (size_t)NPAD * KPAD;          // 4*128*64
    unsigned short* aggbuf = webt + 4 * 128 * 64;                  // N*256
    unsigned short* qbuf   = aggbuf + (size_t)N_NODES * 256;       // N*512
    unsigned char*  kvb    = (unsigned char*)(qbuf + (size_t)N_NODES * 512); // N*4*256 bytes
    int* hist       = (int*)(kvb + (size_t)N_NODES * 4 * 256);     // N
    int* offsets    = hist + N_NODES;                              // N+1
    int* cursor     = offsets + N_NODES + 1;                       // N
    int* sorted_src = cursor + N_NODES;                            // E

    prep_weights_kernel<<<PREP_BLOCKS + TRANS_TILES + WQE_BLOCKS + WEBT_BLOCKS,
                          256, 0, stream>>>(
        nf, frac, lat, n2g, gamma, beta,
        Wq, bq, Wk, bk, Wv, bv, Wsk, bsk, We,
        xb, hist, wallT, bias_all, webt);

    hist_kernel<<<(N_EDGES + 255) / 256, 256, 0, stream>>>(eidx, hist);
    scan_kernel<<<1, 1024, 0, stream>>>(hist, offsets, cursor);

    gemm_scatter_kernel<<<SCAT_BLOCKS + GEMM_BX * GEMM_BY, 256, 0, stream>>>(
        xb, wallT, bias_all, eidx, fdiff, cursor, sorted_src, sorted_fd,
        sq, qbuf, kvb);

    gather_kernel<<<N_NODES, 256, 0, stream>>>(
        sq, qbuf, kvb, offsets, sorted_src, sorted_fd, avbuf, aggbuf, sumwbuf);

    corr_kernel<<<(N_NODES + 31) / 32, 256, 0, stream>>>(webt, aggbuf, avbuf);

    finalize_kernel<<<(N_NODES * CHAN + 255) / 256, 256, 0, stream>>>(
        avbuf, sumwbuf, sq, nf, out);
}